// Round 7
// baseline (172.480 us; speedup 1.0000x reference)
//
#include <hip/hip_runtime.h>

// GCN 2-layer + linear head on MI355X.
// out = relu(agg(relu(agg(X)@W1 + b1)@W2) + b2) @ Wl + bl
// agg(Y) = D^-1/2 (A+I) D^-1/2 Y  (commutes with the dense transform; layer 1
// aggregates X at 26 feats, layer 2 transforms first at 32 feats).
//
// Build (NO global atomics): coarse per-(bucket,block) LDS hist -> 2-level scan ->
// bucket scatter of packed (src<<7|dstlow) -> per-bucket kernel: LDS degree count,
// LDS scan -> dis/offs, LDS-atomic re-scatter to node-sorted 4B src slots, and
// fused prescale xs = dis*x into padded 32-float rows (128B aligned).
// Aggregation: per-node 32-lane gather groups, 8 edges in flight.
// Dense middle: node-per-lane, features in VGPRs, weights via wave-uniform s_load
// (pre-transposed W1t/W2t) -> no LDS reads in the FMA loops.

#define TPB 256
#define GTPB 64              // gemm12: one wave, one node per lane
#define NPB 128              // nodes per bucket (dstlow = 7 bits)
#define EPB 8192             // edges per hist/scatter block
#define NBUCK_MAX 1024

// ---- build -----------------------------------------------------------------

__global__ __launch_bounds__(TPB) void coarse_hist_kernel(
        const int* __restrict__ dst, int* __restrict__ H, int e, int nbuck, int eb) {
    __shared__ int lh[NBUCK_MAX];
    int t = threadIdx.x;
    for (int b = t; b < nbuck; b += TPB) lh[b] = 0;
    __syncthreads();
    int j0 = blockIdx.x * EPB;
    int j1 = min(e, j0 + EPB);
    for (int j = j0 + t; j < j1; j += TPB)
        atomicAdd(&lh[dst[j] >> 7], 1);
    __syncthreads();
    for (int b = t; b < nbuck; b += TPB)
        H[b * eb + blockIdx.x] = lh[b];
}

__global__ __launch_bounds__(TPB) void scan_block_kernel(
        const int* __restrict__ in, int* __restrict__ outx, int* __restrict__ bsum, int m) {
    __shared__ int s[TPB];
    int i = blockIdx.x * TPB + threadIdx.x;
    int v = (i < m) ? in[i] : 0;
    s[threadIdx.x] = v;
    __syncthreads();
#pragma unroll
    for (int d = 1; d < TPB; d <<= 1) {
        int t = (threadIdx.x >= d) ? s[threadIdx.x - d] : 0;
        __syncthreads();
        s[threadIdx.x] += t;
        __syncthreads();
    }
    if (i < m) outx[i] = s[threadIdx.x] - v;  // exclusive
    if (threadIdx.x == TPB - 1) bsum[blockIdx.x] = s[TPB - 1];
}

__global__ __launch_bounds__(512) void scan_bsum_kernel(int* bsum, int nb) {  // nb <= 512
    __shared__ int s[512];
    int i = threadIdx.x;
    int v = (i < nb) ? bsum[i] : 0;
    s[i] = v;
    __syncthreads();
#pragma unroll
    for (int d = 1; d < 512; d <<= 1) {
        int t = (i >= d) ? s[i - d] : 0;
        __syncthreads();
        s[i] += t;
        __syncthreads();
    }
    if (i < nb) bsum[i] = s[i] - v;
}

__global__ __launch_bounds__(TPB) void add_offs_kernel(
        int* __restrict__ SH, const int* __restrict__ bsum, int m) {
    int i = blockIdx.x * TPB + threadIdx.x;
    if (i < m) SH[i] += bsum[i >> 8];
}

__global__ __launch_bounds__(TPB) void bucket_scatter_kernel(
        const int* __restrict__ src, const int* __restrict__ dst,
        const int* __restrict__ SH, int* __restrict__ sortedb, int e, int nbuck, int eb) {
    __shared__ int lc[NBUCK_MAX];
    int t = threadIdx.x;
    for (int b = t; b < nbuck; b += TPB) lc[b] = SH[b * eb + blockIdx.x];
    __syncthreads();
    int j0 = blockIdx.x * EPB;
    int j1 = min(e, j0 + EPB);
    for (int j = j0 + t; j < j1; j += TPB) {
        int d = dst[j];
        int s = src[j];
        int pos = atomicAdd(&lc[d >> 7], 1);   // LDS atomic only
        sortedb[pos] = (s << 7) | (d & 127);
    }
}

// per bucket: degree count -> dis/offs (LDS scan), node-sorted src slots, and
// fused prescale xs[g][0:32] = {dis[g]*x[g][0:26], 0...}  (padded 128B rows)
__global__ __launch_bounds__(TPB) void bucket_sort_fill_kernel(
        const int* __restrict__ sortedb, const int* __restrict__ SH,
        const float* __restrict__ x,
        int* __restrict__ slot, float* __restrict__ dis, int* __restrict__ offs,
        float* __restrict__ xs, int e, int n, int nbuck, int eb) {
    __shared__ int c[NPB];
    __shared__ int ptr[NPB];
    __shared__ float sdis[NPB];
    int b = blockIdx.x, t = threadIdx.x;
    if (t < NPB) c[t] = 0;
    __syncthreads();
    int start = SH[b * eb];
    int end = (b + 1 < nbuck) ? SH[(b + 1) * eb] : e;
    for (int j = start + t; j < end; j += TPB)
        atomicAdd(&c[sortedb[j] & 127], 1);
    __syncthreads();
    int mycnt = (t < NPB) ? c[t] : 0;
    // inclusive Hillis-Steele scan over 128 entries
    for (int d = 1; d < NPB; d <<= 1) {
        int v = 0;
        if (t < NPB && t >= d) v = c[t - d];
        __syncthreads();
        if (t < NPB) c[t] += v;
        __syncthreads();
    }
    if (t < NPB) {
        int excl = c[t] - mycnt;
        ptr[t] = excl;
        float dv = rsqrtf((float)mycnt + 1.0f);
        sdis[t] = dv;
        int g = b * NPB + t;
        if (g < n) {
            dis[g] = dv;
            offs[g] = start + excl;
        }
    }
    if (b == nbuck - 1 && t == 0) offs[n] = e;
    __syncthreads();
    for (int j = start + t; j < end; j += TPB) {
        int w = sortedb[j];
        int pos = atomicAdd(&ptr[w & 127], 1);  // LDS atomic only
        slot[start + pos] = w >> 7;
    }
    // fused prescale (padded rows)
    int base = b * NPB;
    for (int i = t; i < NPB * 32; i += TPB) {
        int r = i >> 5, lane = i & 31;
        int g = base + r;
        if (g < n)
            xs[(size_t)g * 32 + lane] =
                (lane < 26) ? sdis[r] * x[(size_t)g * 26 + lane] : 0.0f;
    }
}

// ---- weight pre-transpose (one block) ---------------------------------------
// W1t[64][32]: W1t[f*32+k] = W1[k*64+f] (k<26; pad 0). W2t[32][64]: W2t[f*64+k] = W2[k*32+f].

__global__ __launch_bounds__(TPB) void transpose_w_kernel(
        const float* __restrict__ W1, const float* __restrict__ W2,
        float* __restrict__ W1t, float* __restrict__ W2t) {
    int t = threadIdx.x;
    for (int i = t; i < 64 * 32; i += TPB) {
        int f = i >> 5, k = i & 31;
        W1t[i] = (k < 26) ? W1[k * 64 + f] : 0.0f;
    }
    for (int i = t; i < 32 * 64; i += TPB) {
        int f = i >> 6, k = i & 63;
        W2t[i] = W2[k * 32 + f];
    }
}

// ---- layer 1 gather: sum1[g][f] = xs[g][f] + sum_edges xs[s][f]  (stride 32) --

__global__ __launch_bounds__(TPB) void gather1_kernel(
        const float* __restrict__ xs, const int* __restrict__ offs,
        const int* __restrict__ slot, float* __restrict__ sum1, int n) {
    int sub = threadIdx.x >> 5;
    int f = threadIdx.x & 31;
    int node = blockIdx.x * 8 + sub;
    if (node >= n) return;
    int j = offs[node], end = offs[node + 1];
    float acc = xs[(size_t)node * 32 + f];
    for (; j + 7 < end; j += 8) {
        int s0 = slot[j], s1 = slot[j + 1], s2 = slot[j + 2], s3 = slot[j + 3];
        int s4 = slot[j + 4], s5 = slot[j + 5], s6 = slot[j + 6], s7 = slot[j + 7];
        float v0 = xs[(size_t)s0 * 32 + f];
        float v1 = xs[(size_t)s1 * 32 + f];
        float v2 = xs[(size_t)s2 * 32 + f];
        float v3 = xs[(size_t)s3 * 32 + f];
        float v4 = xs[(size_t)s4 * 32 + f];
        float v5 = xs[(size_t)s5 * 32 + f];
        float v6 = xs[(size_t)s6 * 32 + f];
        float v7 = xs[(size_t)s7 * 32 + f];
        acc += ((v0 + v1) + (v2 + v3)) + ((v4 + v5) + (v6 + v7));
    }
    for (; j + 3 < end; j += 4) {
        int s0 = slot[j], s1 = slot[j + 1], s2 = slot[j + 2], s3 = slot[j + 3];
        float v0 = xs[(size_t)s0 * 32 + f];
        float v1 = xs[(size_t)s1 * 32 + f];
        float v2 = xs[(size_t)s2 * 32 + f];
        float v3 = xs[(size_t)s3 * 32 + f];
        acc += (v0 + v1) + (v2 + v3);
    }
    for (; j < end; ++j) acc += xs[(size_t)slot[j] * 32 + f];
    sum1[(size_t)node * 32 + f] = acc;   // pad lanes write 0-sums; fully coalesced
}

// ---- fused dense middle, node-per-lane --------------------------------------
// xw2s[g] = dis[g] * (relu(dis[g]*sum1[g] @ W1 + b1) @ W2)
// Features in VGPRs (static indices); weights/bias via wave-uniform s_load.

__global__ __launch_bounds__(GTPB) void gemm12_kernel(
        const float* __restrict__ sum1, const float* __restrict__ dis,
        const float* __restrict__ W1t, const float* __restrict__ b1,
        const float* __restrict__ W2t, float* __restrict__ xw2s, int n) {
    __shared__ float sh2[GTPB][33];
    int t = threadIdx.x;
    int node0 = blockIdx.x * GTPB;
    int g = node0 + t;
    bool valid = (g < n);
    int gl = valid ? g : 0;

    // load own feature row (26 useful floats of the padded 32-float row)
    float xr[28];
    const float* rp = sum1 + (size_t)gl * 32;
#pragma unroll
    for (int q = 0; q < 7; ++q) {
        float4 v = *(const float4*)(rp + q * 4);
        xr[q * 4 + 0] = v.x; xr[q * 4 + 1] = v.y;
        xr[q * 4 + 2] = v.z; xr[q * 4 + 3] = v.w;
    }
    float dv = valid ? dis[gl] : 0.0f;

    // phase 1: h1r[f] = relu(dv * <xr, W1t[f]> + b1[f])   (fully unrolled: static idx)
    float h1r[64];
#pragma unroll
    for (int f = 0; f < 64; ++f) {
        float a0 = 0.0f, a1 = 0.0f;
#pragma unroll
        for (int k = 0; k < 26; k += 2) {
            a0 += xr[k] * W1t[f * 32 + k];
            a1 += xr[k + 1] * W1t[f * 32 + k + 1];
        }
        h1r[f] = fmaxf(dv * (a0 + a1) + b1[f], 0.0f);
    }

    // phase 2: sh2[t][f2] = dv * <h1r, W2t[f2]>   (h1r static idx; weights uniform)
    for (int f2 = 0; f2 < 32; ++f2) {
        float a0 = 0.0f, a1 = 0.0f, a2 = 0.0f, a3 = 0.0f;
#pragma unroll
        for (int k = 0; k < 64; k += 4) {
            a0 += h1r[k] * W2t[f2 * 64 + k];
            a1 += h1r[k + 1] * W2t[f2 * 64 + k + 1];
            a2 += h1r[k + 2] * W2t[f2 * 64 + k + 2];
            a3 += h1r[k + 3] * W2t[f2 * 64 + k + 3];
        }
        sh2[t][f2] = dv * ((a0 + a1) + (a2 + a3));
    }
    __syncthreads();

    // coalesced tile store
    for (int i = t; i < GTPB * 32; i += GTPB) {
        int r = i >> 5, ccol = i & 31;
        if (node0 + r < n)
            xw2s[(size_t)node0 * 32 + i] = sh2[r][ccol];
    }
}

// ---- layer 2 gather + bias + relu + head, fused ------------------------------

__global__ __launch_bounds__(TPB) void gather2_head_kernel(
        const float* __restrict__ xw2s, const float* __restrict__ dis,
        const int* __restrict__ offs, const int* __restrict__ slot,
        const float* __restrict__ b2, const float* __restrict__ Wl,
        const float* __restrict__ bl, float* __restrict__ out, int n) {
    int sub = threadIdx.x >> 5;
    int f = threadIdx.x & 31;
    int node = blockIdx.x * 8 + sub;
    if (node >= n) return;
    int j = offs[node], end = offs[node + 1];
    float acc = xw2s[(size_t)node * 32 + f];
    for (; j + 7 < end; j += 8) {
        int s0 = slot[j], s1 = slot[j + 1], s2 = slot[j + 2], s3 = slot[j + 3];
        int s4 = slot[j + 4], s5 = slot[j + 5], s6 = slot[j + 6], s7 = slot[j + 7];
        float v0 = xw2s[(size_t)s0 * 32 + f];
        float v1 = xw2s[(size_t)s1 * 32 + f];
        float v2 = xw2s[(size_t)s2 * 32 + f];
        float v3 = xw2s[(size_t)s3 * 32 + f];
        float v4 = xw2s[(size_t)s4 * 32 + f];
        float v5 = xw2s[(size_t)s5 * 32 + f];
        float v6 = xw2s[(size_t)s6 * 32 + f];
        float v7 = xw2s[(size_t)s7 * 32 + f];
        acc += ((v0 + v1) + (v2 + v3)) + ((v4 + v5) + (v6 + v7));
    }
    for (; j + 3 < end; j += 4) {
        int s0 = slot[j], s1 = slot[j + 1], s2 = slot[j + 2], s3 = slot[j + 3];
        float v0 = xw2s[(size_t)s0 * 32 + f];
        float v1 = xw2s[(size_t)s1 * 32 + f];
        float v2 = xw2s[(size_t)s2 * 32 + f];
        float v3 = xw2s[(size_t)s3 * 32 + f];
        acc += (v0 + v1) + (v2 + v3);
    }
    for (; j < end; ++j) acc += xw2s[(size_t)slot[j] * 32 + f];
    float v = fmaxf(dis[node] * acc + b2[f], 0.0f);
    float c = v * Wl[f];
#pragma unroll
    for (int mm = 16; mm >= 1; mm >>= 1) c += __shfl_xor(c, mm, 32);
    if (f == 0) out[node] = c + bl[0];
}

// ---- host ------------------------------------------------------------------

extern "C" void kernel_launch(void* const* d_in, const int* in_sizes, int n_in,
                              void* d_out, int out_size, void* d_ws, size_t ws_size,
                              hipStream_t stream) {
    const float* x  = (const float*)d_in[0];
    const int*   ei = (const int*)d_in[1];
    const float* W1 = (const float*)d_in[2];
    const float* b1 = (const float*)d_in[3];
    const float* W2 = (const float*)d_in[4];
    const float* b2 = (const float*)d_in[5];
    const float* Wl = (const float*)d_in[6];
    const float* bl = (const float*)d_in[7];
    float* out = (float*)d_out;

    const int n = in_sizes[0] / 26;
    const int e = in_sizes[1] / 2;
    const int* src = ei;
    const int* dst = ei + e;

    const int nbuck = (n + NPB - 1) / NPB;   // 782 (<= NBUCK_MAX)
    const int eb    = (e + EPB - 1) / EPB;   // 147
    const int m     = nbuck * eb;            // ~115k
    const int msb   = (m + TPB - 1) / TPB;   // 450 (<= 512)

    auto align_up = [](size_t v) { return (v + 255) & ~(size_t)255; };
    char* p = (char*)d_ws;
    int*   H       = (int*)p;    p += align_up((size_t)m * 4);
    int*   SH      = (int*)p;    p += align_up((size_t)m * 4);
    int*   bsum    = (int*)p;    p += align_up(512 * 4);
    int*   sortedb = (int*)p;    p += align_up((size_t)e * 4);
    int*   slot    = (int*)p;    p += align_up((size_t)e * 4);
    float* dis     = (float*)p;  p += align_up((size_t)n * 4);
    int*   offs    = (int*)p;    p += align_up((size_t)(n + 1) * 4);
    float* W1t     = (float*)p;  p += align_up(64 * 32 * 4);
    float* W2t     = (float*)p;  p += align_up(32 * 64 * 4);
    float* xs      = (float*)p;  p += align_up((size_t)n * 32 * 4);
    float* sum1    = (float*)p;  p += align_up((size_t)n * 32 * 4);
    float* xw2s    = (float*)p;  p += align_up((size_t)n * 32 * 4);

    // 0) weight pre-transpose (tiny, one block)
    transpose_w_kernel<<<1, TPB, 0, stream>>>(W1, W2, W1t, W2t);

    // 1) bucket-sorted CSR build (no global atomics anywhere) + fused prescale
    coarse_hist_kernel<<<eb, TPB, 0, stream>>>(dst, H, e, nbuck, eb);
    scan_block_kernel<<<msb, TPB, 0, stream>>>(H, SH, bsum, m);
    scan_bsum_kernel<<<1, 512, 0, stream>>>(bsum, msb);
    add_offs_kernel<<<msb, TPB, 0, stream>>>(SH, bsum, m);
    bucket_scatter_kernel<<<eb, TPB, 0, stream>>>(src, dst, SH, sortedb, e, nbuck, eb);
    bucket_sort_fill_kernel<<<nbuck, TPB, 0, stream>>>(sortedb, SH, x, slot, dis, offs,
                                                       xs, e, n, nbuck, eb);

    // 2) layer 1 gather (26 feats, padded rows)
    gather1_kernel<<<(n + 7) / 8, TPB, 0, stream>>>(xs, offs, slot, sum1, n);

    // 3) fused dense middle (node-per-lane, scalar-load weights)
    gemm12_kernel<<<(n + GTPB - 1) / GTPB, GTPB, 0, stream>>>(sum1, dis, W1t, b1, W2t,
                                                              xw2s, n);

    // 4) layer 2 gather + bias + relu + head (fused)
    gather2_head_kernel<<<(n + 7) / 8, TPB, 0, stream>>>(xw2s, dis, offs, slot,
                                                         b2, Wl, bl, out, n);
}

// Round 8
// 144.019 us; speedup vs baseline: 1.1976x; 1.1976x over previous
//
#include <hip/hip_runtime.h>

// GCN 2-layer + linear head on MI355X.
// out = relu(agg(relu(agg(X)@W1 + b1)@W2) + b2) @ Wl + bl
// agg(Y) = D^-1/2 (A+I) D^-1/2 Y  (commutes with the dense transform; layer 1
// aggregates X at 26 feats, layer 2 transforms first at 32 feats).
//
// Build (NO global atomics): coarse per-(bucket,block) LDS hist -> 2-level scan ->
// bucket scatter of packed (src<<7|dstlow) -> per-bucket kernel: LDS degree count,
// LDS scan -> dis/offs, LDS-atomic re-scatter to node-sorted 4B src slots, and
// fused prescale xs = dis*x into padded 32-float rows (128B aligned).
// Aggregation: per-node 32-lane gather groups, 8 edges in flight.
// Dense middle: lane=node, f split across the block's 4 waves; weights via
// wave-uniform s_load (readfirstlane-forced); h1 round-trips through LDS.

#define TPB 256
#define NPB 128              // nodes per bucket (dstlow = 7 bits)
#define EPB 8192             // edges per hist/scatter block
#define NBUCK_MAX 1024

// ---- build -----------------------------------------------------------------

__global__ __launch_bounds__(TPB) void coarse_hist_kernel(
        const int* __restrict__ dst, int* __restrict__ H, int e, int nbuck, int eb) {
    __shared__ int lh[NBUCK_MAX];
    int t = threadIdx.x;
    for (int b = t; b < nbuck; b += TPB) lh[b] = 0;
    __syncthreads();
    int j0 = blockIdx.x * EPB;
    int j1 = min(e, j0 + EPB);
    for (int j = j0 + t; j < j1; j += TPB)
        atomicAdd(&lh[dst[j] >> 7], 1);
    __syncthreads();
    for (int b = t; b < nbuck; b += TPB)
        H[b * eb + blockIdx.x] = lh[b];
}

__global__ __launch_bounds__(TPB) void scan_block_kernel(
        const int* __restrict__ in, int* __restrict__ outx, int* __restrict__ bsum, int m) {
    __shared__ int s[TPB];
    int i = blockIdx.x * TPB + threadIdx.x;
    int v = (i < m) ? in[i] : 0;
    s[threadIdx.x] = v;
    __syncthreads();
#pragma unroll
    for (int d = 1; d < TPB; d <<= 1) {
        int t = (threadIdx.x >= d) ? s[threadIdx.x - d] : 0;
        __syncthreads();
        s[threadIdx.x] += t;
        __syncthreads();
    }
    if (i < m) outx[i] = s[threadIdx.x] - v;  // exclusive
    if (threadIdx.x == TPB - 1) bsum[blockIdx.x] = s[TPB - 1];
}

__global__ __launch_bounds__(512) void scan_bsum_kernel(int* bsum, int nb) {  // nb <= 512
    __shared__ int s[512];
    int i = threadIdx.x;
    int v = (i < nb) ? bsum[i] : 0;
    s[i] = v;
    __syncthreads();
#pragma unroll
    for (int d = 1; d < 512; d <<= 1) {
        int t = (i >= d) ? s[i - d] : 0;
        __syncthreads();
        s[i] += t;
        __syncthreads();
    }
    if (i < nb) bsum[i] = s[i] - v;
}

__global__ __launch_bounds__(TPB) void add_offs_kernel(
        int* __restrict__ SH, const int* __restrict__ bsum, int m) {
    int i = blockIdx.x * TPB + threadIdx.x;
    if (i < m) SH[i] += bsum[i >> 8];
}

__global__ __launch_bounds__(TPB) void bucket_scatter_kernel(
        const int* __restrict__ src, const int* __restrict__ dst,
        const int* __restrict__ SH, int* __restrict__ sortedb, int e, int nbuck, int eb) {
    __shared__ int lc[NBUCK_MAX];
    int t = threadIdx.x;
    for (int b = t; b < nbuck; b += TPB) lc[b] = SH[b * eb + blockIdx.x];
    __syncthreads();
    int j0 = blockIdx.x * EPB;
    int j1 = min(e, j0 + EPB);
    for (int j = j0 + t; j < j1; j += TPB) {
        int d = dst[j];
        int s = src[j];
        int pos = atomicAdd(&lc[d >> 7], 1);   // LDS atomic only
        sortedb[pos] = (s << 7) | (d & 127);
    }
}

// per bucket: degree count -> dis/offs (LDS scan), node-sorted src slots, and
// fused prescale xs[g][0:32] = {dis[g]*x[g][0:26], 0...}  (padded 128B rows)
__global__ __launch_bounds__(TPB) void bucket_sort_fill_kernel(
        const int* __restrict__ sortedb, const int* __restrict__ SH,
        const float* __restrict__ x,
        int* __restrict__ slot, float* __restrict__ dis, int* __restrict__ offs,
        float* __restrict__ xs, int e, int n, int nbuck, int eb) {
    __shared__ int c[NPB];
    __shared__ int ptr[NPB];
    __shared__ float sdis[NPB];
    int b = blockIdx.x, t = threadIdx.x;
    if (t < NPB) c[t] = 0;
    __syncthreads();
    int start = SH[b * eb];
    int end = (b + 1 < nbuck) ? SH[(b + 1) * eb] : e;
    for (int j = start + t; j < end; j += TPB)
        atomicAdd(&c[sortedb[j] & 127], 1);
    __syncthreads();
    int mycnt = (t < NPB) ? c[t] : 0;
    // inclusive Hillis-Steele scan over 128 entries
    for (int d = 1; d < NPB; d <<= 1) {
        int v = 0;
        if (t < NPB && t >= d) v = c[t - d];
        __syncthreads();
        if (t < NPB) c[t] += v;
        __syncthreads();
    }
    if (t < NPB) {
        int excl = c[t] - mycnt;
        ptr[t] = excl;
        float dv = rsqrtf((float)mycnt + 1.0f);
        sdis[t] = dv;
        int g = b * NPB + t;
        if (g < n) {
            dis[g] = dv;
            offs[g] = start + excl;
        }
    }
    if (b == nbuck - 1 && t == 0) offs[n] = e;
    __syncthreads();
    for (int j = start + t; j < end; j += TPB) {
        int w = sortedb[j];
        int pos = atomicAdd(&ptr[w & 127], 1);  // LDS atomic only
        slot[start + pos] = w >> 7;
    }
    // fused prescale (padded rows)
    int base = b * NPB;
    for (int i = t; i < NPB * 32; i += TPB) {
        int r = i >> 5, lane = i & 31;
        int g = base + r;
        if (g < n)
            xs[(size_t)g * 32 + lane] =
                (lane < 26) ? sdis[r] * x[(size_t)g * 26 + lane] : 0.0f;
    }
}

// ---- weight pre-transpose (one block) ---------------------------------------
// W1t[64][32]: W1t[f*32+k] = W1[k*64+f] (k<26; pad 0). W2t[32][64]: W2t[f*64+k] = W2[k*32+f].

__global__ __launch_bounds__(TPB) void transpose_w_kernel(
        const float* __restrict__ W1, const float* __restrict__ W2,
        float* __restrict__ W1t, float* __restrict__ W2t) {
    int t = threadIdx.x;
    for (int i = t; i < 64 * 32; i += TPB) {
        int f = i >> 5, k = i & 31;
        W1t[i] = (k < 26) ? W1[k * 64 + f] : 0.0f;
    }
    for (int i = t; i < 32 * 64; i += TPB) {
        int f = i >> 6, k = i & 63;
        W2t[i] = W2[k * 32 + f];
    }
}

// ---- layer 1 gather: sum1[g][f] = xs[g][f] + sum_edges xs[s][f]  (stride 32) --

__global__ __launch_bounds__(TPB) void gather1_kernel(
        const float* __restrict__ xs, const int* __restrict__ offs,
        const int* __restrict__ slot, float* __restrict__ sum1, int n) {
    int sub = threadIdx.x >> 5;
    int f = threadIdx.x & 31;
    int node = blockIdx.x * 8 + sub;
    if (node >= n) return;
    int j = offs[node], end = offs[node + 1];
    float acc = xs[(size_t)node * 32 + f];
    for (; j + 7 < end; j += 8) {
        int s0 = slot[j], s1 = slot[j + 1], s2 = slot[j + 2], s3 = slot[j + 3];
        int s4 = slot[j + 4], s5 = slot[j + 5], s6 = slot[j + 6], s7 = slot[j + 7];
        float v0 = xs[(size_t)s0 * 32 + f];
        float v1 = xs[(size_t)s1 * 32 + f];
        float v2 = xs[(size_t)s2 * 32 + f];
        float v3 = xs[(size_t)s3 * 32 + f];
        float v4 = xs[(size_t)s4 * 32 + f];
        float v5 = xs[(size_t)s5 * 32 + f];
        float v6 = xs[(size_t)s6 * 32 + f];
        float v7 = xs[(size_t)s7 * 32 + f];
        acc += ((v0 + v1) + (v2 + v3)) + ((v4 + v5) + (v6 + v7));
    }
    for (; j + 3 < end; j += 4) {
        int s0 = slot[j], s1 = slot[j + 1], s2 = slot[j + 2], s3 = slot[j + 3];
        float v0 = xs[(size_t)s0 * 32 + f];
        float v1 = xs[(size_t)s1 * 32 + f];
        float v2 = xs[(size_t)s2 * 32 + f];
        float v3 = xs[(size_t)s3 * 32 + f];
        acc += (v0 + v1) + (v2 + v3);
    }
    for (; j < end; ++j) acc += xs[(size_t)slot[j] * 32 + f];
    sum1[(size_t)node * 32 + f] = acc;   // pad lanes write 0-sums; fully coalesced
}

// ---- fused dense middle: 4 waves, lane=node, f split across waves -----------
// xw2s[g] = dis[g] * (relu(dis[g]*sum1[g] @ W1 + b1) @ W2)
// Weights via wave-uniform s_load (readfirstlane); h1 through padded LDS tile.

__global__ __launch_bounds__(TPB) void dense_mid_kernel(
        const float* __restrict__ sum1, const float* __restrict__ dis,
        const float* __restrict__ W1t, const float* __restrict__ b1,
        const float* __restrict__ W2t, float* __restrict__ xw2s, int n) {
    __shared__ float sh1[64][68];   // 17.4 KB, node-major padded (8-way worst)
    __shared__ float sh2[64][33];   // 8.4 KB, conflict-free stores
    int t = threadIdx.x;
    int lane = t & 63;
    int wv = __builtin_amdgcn_readfirstlane(t >> 6);   // wave id 0..3, SGPR-uniform
    int node0 = blockIdx.x * 64;
    int g = node0 + lane;
    int gl = (g < n) ? g : (n - 1);

    // own feature row (26 useful floats of the padded 32-float row)
    float xr[28];
    {
        const float* rp = sum1 + (size_t)gl * 32;
#pragma unroll
        for (int q = 0; q < 7; ++q) {
            float4 v = *(const float4*)(rp + q * 4);
            xr[q * 4 + 0] = v.x; xr[q * 4 + 1] = v.y;
            xr[q * 4 + 2] = v.z; xr[q * 4 + 3] = v.w;
        }
    }
    float dv = dis[gl];

    // phase 1: this wave computes h1[f] for f in [wv*16, wv*16+16)
    {
        const float* Wbase = W1t + wv * 16 * 32;   // uniform
#pragma unroll
        for (int fi = 0; fi < 16; ++fi) {
            const float* Wrow = Wbase + fi * 32;   // uniform -> s_load
            float a0 = 0.0f, a1 = 0.0f;
#pragma unroll
            for (int k = 0; k < 26; k += 2) {
                a0 += xr[k] * Wrow[k];
                a1 += xr[k + 1] * Wrow[k + 1];
            }
            float h = fmaxf(dv * (a0 + a1) + b1[wv * 16 + fi], 0.0f);
            sh1[lane][wv * 16 + fi] = h;
        }
    }
    __syncthreads();

    // phase 2: read own h1 row into regs, compute f2 in [wv*8, wv*8+8)
    {
        float h1r[64];
#pragma unroll
        for (int q = 0; q < 16; ++q) {
            float4 v = *(const float4*)(&sh1[lane][q * 4]);
            h1r[q * 4 + 0] = v.x; h1r[q * 4 + 1] = v.y;
            h1r[q * 4 + 2] = v.z; h1r[q * 4 + 3] = v.w;
        }
        const float* Wbase2 = W2t + wv * 8 * 64;   // uniform
#pragma unroll
        for (int fi = 0; fi < 8; ++fi) {
            const float* Wrow = Wbase2 + fi * 64;  // uniform -> s_load
            float a0 = 0.0f, a1 = 0.0f, a2 = 0.0f, a3 = 0.0f;
#pragma unroll
            for (int k = 0; k < 64; k += 4) {
                a0 += h1r[k] * Wrow[k];
                a1 += h1r[k + 1] * Wrow[k + 1];
                a2 += h1r[k + 2] * Wrow[k + 2];
                a3 += h1r[k + 3] * Wrow[k + 3];
            }
            sh2[lane][wv * 8 + fi] = dv * (((a0 + a1) + (a2 + a3)));
        }
    }
    __syncthreads();

    // coalesced tile store
    for (int i = t; i < 64 * 32; i += TPB) {
        int r = i >> 5, ccol = i & 31;
        if (node0 + r < n)
            xw2s[(size_t)(node0 + r) * 32 + ccol] = sh2[r][ccol];
    }
}

// ---- layer 2 gather + bias + relu + head, fused ------------------------------

__global__ __launch_bounds__(TPB) void gather2_head_kernel(
        const float* __restrict__ xw2s, const float* __restrict__ dis,
        const int* __restrict__ offs, const int* __restrict__ slot,
        const float* __restrict__ b2, const float* __restrict__ Wl,
        const float* __restrict__ bl, float* __restrict__ out, int n) {
    int sub = threadIdx.x >> 5;
    int f = threadIdx.x & 31;
    int node = blockIdx.x * 8 + sub;
    if (node >= n) return;
    int j = offs[node], end = offs[node + 1];
    float acc = xw2s[(size_t)node * 32 + f];
    for (; j + 7 < end; j += 8) {
        int s0 = slot[j], s1 = slot[j + 1], s2 = slot[j + 2], s3 = slot[j + 3];
        int s4 = slot[j + 4], s5 = slot[j + 5], s6 = slot[j + 6], s7 = slot[j + 7];
        float v0 = xw2s[(size_t)s0 * 32 + f];
        float v1 = xw2s[(size_t)s1 * 32 + f];
        float v2 = xw2s[(size_t)s2 * 32 + f];
        float v3 = xw2s[(size_t)s3 * 32 + f];
        float v4 = xw2s[(size_t)s4 * 32 + f];
        float v5 = xw2s[(size_t)s5 * 32 + f];
        float v6 = xw2s[(size_t)s6 * 32 + f];
        float v7 = xw2s[(size_t)s7 * 32 + f];
        acc += ((v0 + v1) + (v2 + v3)) + ((v4 + v5) + (v6 + v7));
    }
    for (; j + 3 < end; j += 4) {
        int s0 = slot[j], s1 = slot[j + 1], s2 = slot[j + 2], s3 = slot[j + 3];
        float v0 = xw2s[(size_t)s0 * 32 + f];
        float v1 = xw2s[(size_t)s1 * 32 + f];
        float v2 = xw2s[(size_t)s2 * 32 + f];
        float v3 = xw2s[(size_t)s3 * 32 + f];
        acc += (v0 + v1) + (v2 + v3);
    }
    for (; j < end; ++j) acc += xw2s[(size_t)slot[j] * 32 + f];
    float v = fmaxf(dis[node] * acc + b2[f], 0.0f);
    float c = v * Wl[f];
#pragma unroll
    for (int mm = 16; mm >= 1; mm >>= 1) c += __shfl_xor(c, mm, 32);
    if (f == 0) out[node] = c + bl[0];
}

// ---- host ------------------------------------------------------------------

extern "C" void kernel_launch(void* const* d_in, const int* in_sizes, int n_in,
                              void* d_out, int out_size, void* d_ws, size_t ws_size,
                              hipStream_t stream) {
    const float* x  = (const float*)d_in[0];
    const int*   ei = (const int*)d_in[1];
    const float* W1 = (const float*)d_in[2];
    const float* b1 = (const float*)d_in[3];
    const float* W2 = (const float*)d_in[4];
    const float* b2 = (const float*)d_in[5];
    const float* Wl = (const float*)d_in[6];
    const float* bl = (const float*)d_in[7];
    float* out = (float*)d_out;

    const int n = in_sizes[0] / 26;
    const int e = in_sizes[1] / 2;
    const int* src = ei;
    const int* dst = ei + e;

    const int nbuck = (n + NPB - 1) / NPB;   // 782 (<= NBUCK_MAX)
    const int eb    = (e + EPB - 1) / EPB;   // 147
    const int m     = nbuck * eb;            // ~115k
    const int msb   = (m + TPB - 1) / TPB;   // 450 (<= 512)

    auto align_up = [](size_t v) { return (v + 255) & ~(size_t)255; };
    char* p = (char*)d_ws;
    int*   H       = (int*)p;    p += align_up((size_t)m * 4);
    int*   SH      = (int*)p;    p += align_up((size_t)m * 4);
    int*   bsum    = (int*)p;    p += align_up(512 * 4);
    int*   sortedb = (int*)p;    p += align_up((size_t)e * 4);
    int*   slot    = (int*)p;    p += align_up((size_t)e * 4);
    float* dis     = (float*)p;  p += align_up((size_t)n * 4);
    int*   offs    = (int*)p;    p += align_up((size_t)(n + 1) * 4);
    float* W1t     = (float*)p;  p += align_up(64 * 32 * 4);
    float* W2t     = (float*)p;  p += align_up(32 * 64 * 4);
    float* xs      = (float*)p;  p += align_up((size_t)n * 32 * 4);
    float* sum1    = (float*)p;  p += align_up((size_t)n * 32 * 4);
    float* xw2s    = (float*)p;  p += align_up((size_t)n * 32 * 4);

    // 0) weight pre-transpose (tiny, one block)
    transpose_w_kernel<<<1, TPB, 0, stream>>>(W1, W2, W1t, W2t);

    // 1) bucket-sorted CSR build (no global atomics anywhere) + fused prescale
    coarse_hist_kernel<<<eb, TPB, 0, stream>>>(dst, H, e, nbuck, eb);
    scan_block_kernel<<<msb, TPB, 0, stream>>>(H, SH, bsum, m);
    scan_bsum_kernel<<<1, 512, 0, stream>>>(bsum, msb);
    add_offs_kernel<<<msb, TPB, 0, stream>>>(SH, bsum, m);
    bucket_scatter_kernel<<<eb, TPB, 0, stream>>>(src, dst, SH, sortedb, e, nbuck, eb);
    bucket_sort_fill_kernel<<<nbuck, TPB, 0, stream>>>(sortedb, SH, x, slot, dis, offs,
                                                       xs, e, n, nbuck, eb);

    // 2) layer 1 gather (26 feats, padded rows)
    gather1_kernel<<<(n + 7) / 8, TPB, 0, stream>>>(xs, offs, slot, sum1, n);

    // 3) fused dense middle (4-wave split-f, scalar-load weights)
    dense_mid_kernel<<<(n + 63) / 64, TPB, 0, stream>>>(sum1, dis, W1t, b1, W2t, xw2s, n);

    // 4) layer 2 gather + bias + relu + head (fused)
    gather2_head_kernel<<<(n + 7) / 8, TPB, 0, stream>>>(xw2s, dis, offs, slot,
                                                         b2, Wl, bl, out, n);
}

// Round 9
// 136.739 us; speedup vs baseline: 1.2614x; 1.0532x over previous
//
#include <hip/hip_runtime.h>
#include <hip/hip_fp16.h>

// GCN 2-layer + linear head on MI355X.
// out = relu(agg(relu(agg(X)@W1 + b1)@W2) + b2) @ Wl + bl
// agg(Y) = D^-1/2 (A+I) D^-1/2 Y  (commutes with the dense transform; layer 1
// aggregates X at 26 feats, layer 2 transforms first at 32 feats).
//
// Build (NO global atomics): coarse per-(bucket,block) LDS hist -> 2-level scan
// (bsum add folded into consumers) -> bucket scatter of packed (src<<7|dstlow) ->
// per-bucket kernel: LDS degree count, LDS scan -> dis/offs, LDS-atomic re-scatter
// to node-sorted 4B src slots, fused prescale xs = fp16(dis*x) (64B rows).
// Gather tables xs/xw2s are fp16 (halves random-read bytes AND working set ->
// L2-resident); accumulation in fp32. Dense middle: lane=node, f split across
// 4 waves, weights via wave-uniform s_load.

#define TPB 256
#define NPB 128              // nodes per bucket (dstlow = 7 bits)
#define EPB 8192             // edges per hist/scatter block
#define NBUCK_MAX 1024

// ---- build -----------------------------------------------------------------

__global__ __launch_bounds__(TPB) void coarse_hist_kernel(
        const int* __restrict__ dst, int* __restrict__ H, int e, int nbuck, int eb) {
    __shared__ int lh[NBUCK_MAX];
    int t = threadIdx.x;
    for (int b = t; b < nbuck; b += TPB) lh[b] = 0;
    __syncthreads();
    int j0 = blockIdx.x * EPB;
    int j1 = min(e, j0 + EPB);
    for (int j = j0 + t; j < j1; j += TPB)
        atomicAdd(&lh[dst[j] >> 7], 1);
    __syncthreads();
    for (int b = t; b < nbuck; b += TPB)
        H[b * eb + blockIdx.x] = lh[b];
}

__global__ __launch_bounds__(TPB) void scan_block_kernel(
        const int* __restrict__ in, int* __restrict__ outx, int* __restrict__ bsum, int m) {
    __shared__ int s[TPB];
    int i = blockIdx.x * TPB + threadIdx.x;
    int v = (i < m) ? in[i] : 0;
    s[threadIdx.x] = v;
    __syncthreads();
#pragma unroll
    for (int d = 1; d < TPB; d <<= 1) {
        int t = (threadIdx.x >= d) ? s[threadIdx.x - d] : 0;
        __syncthreads();
        s[threadIdx.x] += t;
        __syncthreads();
    }
    if (i < m) outx[i] = s[threadIdx.x] - v;  // exclusive
    if (threadIdx.x == TPB - 1) bsum[blockIdx.x] = s[TPB - 1];
}

// exclusive scan of bsum (nb <= 512) + weight pre-transpose (both tiny, fused)
__global__ __launch_bounds__(512) void scan_bsum_transpose_kernel(
        int* bsum, int nb,
        const float* __restrict__ W1, const float* __restrict__ W2,
        float* __restrict__ W1t, float* __restrict__ W2t) {
    __shared__ int s[512];
    int i = threadIdx.x;
    int v = (i < nb) ? bsum[i] : 0;
    s[i] = v;
    __syncthreads();
#pragma unroll
    for (int d = 1; d < 512; d <<= 1) {
        int t = (i >= d) ? s[i - d] : 0;
        __syncthreads();
        s[i] += t;
        __syncthreads();
    }
    if (i < nb) bsum[i] = s[i] - v;
    // W1t[64][32]: W1t[f*32+k] = W1[k*64+f] (k<26; pad 0). W2t[32][64].
    for (int q = i; q < 64 * 32; q += 512) {
        int f = q >> 5, k = q & 31;
        W1t[q] = (k < 26) ? W1[k * 64 + f] : 0.0f;
    }
    for (int q = i; q < 32 * 64; q += 512) {
        int f = q >> 6, k = q & 63;
        W2t[q] = W2[k * 32 + f];
    }
}

__global__ __launch_bounds__(TPB) void bucket_scatter_kernel(
        const int* __restrict__ src, const int* __restrict__ dst,
        const int* __restrict__ SH, const int* __restrict__ bsum,
        int* __restrict__ sortedb, int e, int nbuck, int eb) {
    __shared__ int lc[NBUCK_MAX];
    int t = threadIdx.x;
    for (int b = t; b < nbuck; b += TPB) {
        int idx = b * eb + blockIdx.x;
        lc[b] = SH[idx] + bsum[idx >> 8];
    }
    __syncthreads();
    int j0 = blockIdx.x * EPB;
    int j1 = min(e, j0 + EPB);
    for (int j = j0 + t; j < j1; j += TPB) {
        int d = dst[j];
        int s = src[j];
        int pos = atomicAdd(&lc[d >> 7], 1);   // LDS atomic only
        sortedb[pos] = (s << 7) | (d & 127);
    }
}

// per bucket: degree count -> dis/offs (LDS scan), node-sorted src slots, and
// fused prescale xs[g][0:32] = fp16{dis[g]*x[g][0:26], 0...}  (64B rows)
__global__ __launch_bounds__(TPB) void bucket_sort_fill_kernel(
        const int* __restrict__ sortedb, const int* __restrict__ SH,
        const int* __restrict__ bsum, const float* __restrict__ x,
        int* __restrict__ slot, float* __restrict__ dis, int* __restrict__ offs,
        __half* __restrict__ xs, int e, int n, int nbuck, int eb) {
    __shared__ int c[NPB];
    __shared__ int ptr[NPB];
    __shared__ float sdis[NPB];
    int b = blockIdx.x, t = threadIdx.x;
    if (t < NPB) c[t] = 0;
    __syncthreads();
    int idx0 = b * eb;
    int start = SH[idx0] + bsum[idx0 >> 8];
    int end;
    if (b + 1 < nbuck) {
        int idx1 = (b + 1) * eb;
        end = SH[idx1] + bsum[idx1 >> 8];
    } else {
        end = e;
    }
    for (int j = start + t; j < end; j += TPB)
        atomicAdd(&c[sortedb[j] & 127], 1);
    __syncthreads();
    int mycnt = (t < NPB) ? c[t] : 0;
    // inclusive Hillis-Steele scan over 128 entries
    for (int d = 1; d < NPB; d <<= 1) {
        int v = 0;
        if (t < NPB && t >= d) v = c[t - d];
        __syncthreads();
        if (t < NPB) c[t] += v;
        __syncthreads();
    }
    if (t < NPB) {
        int excl = c[t] - mycnt;
        ptr[t] = excl;
        float dv = rsqrtf((float)mycnt + 1.0f);
        sdis[t] = dv;
        int g = b * NPB + t;
        if (g < n) {
            dis[g] = dv;
            offs[g] = start + excl;
        }
    }
    if (b == nbuck - 1 && t == 0) offs[n] = e;
    __syncthreads();
    for (int j = start + t; j < end; j += TPB) {
        int w = sortedb[j];
        int pos = atomicAdd(&ptr[w & 127], 1);  // LDS atomic only
        slot[start + pos] = w >> 7;
    }
    // fused prescale (fp16 padded rows)
    int base = b * NPB;
    for (int i = t; i < NPB * 32; i += TPB) {
        int r = i >> 5, lane = i & 31;
        int g = base + r;
        if (g < n)
            xs[(size_t)g * 32 + lane] =
                __float2half((lane < 26) ? sdis[r] * x[(size_t)g * 26 + lane] : 0.0f);
    }
}

// ---- layer 1 gather: sum1[g][f] = xs[g][f] + sum_edges xs[s][f]  (fp16 -> f32) --

__global__ __launch_bounds__(TPB) void gather1_kernel(
        const __half* __restrict__ xs, const int* __restrict__ offs,
        const int* __restrict__ slot, float* __restrict__ sum1, int n) {
    int sub = threadIdx.x >> 5;
    int f = threadIdx.x & 31;
    int node = blockIdx.x * 8 + sub;
    if (node >= n) return;
    int j = offs[node], end = offs[node + 1];
    float acc = __half2float(xs[(size_t)node * 32 + f]);
    for (; j + 7 < end; j += 8) {
        int s0 = slot[j], s1 = slot[j + 1], s2 = slot[j + 2], s3 = slot[j + 3];
        int s4 = slot[j + 4], s5 = slot[j + 5], s6 = slot[j + 6], s7 = slot[j + 7];
        float v0 = __half2float(xs[(size_t)s0 * 32 + f]);
        float v1 = __half2float(xs[(size_t)s1 * 32 + f]);
        float v2 = __half2float(xs[(size_t)s2 * 32 + f]);
        float v3 = __half2float(xs[(size_t)s3 * 32 + f]);
        float v4 = __half2float(xs[(size_t)s4 * 32 + f]);
        float v5 = __half2float(xs[(size_t)s5 * 32 + f]);
        float v6 = __half2float(xs[(size_t)s6 * 32 + f]);
        float v7 = __half2float(xs[(size_t)s7 * 32 + f]);
        acc += ((v0 + v1) + (v2 + v3)) + ((v4 + v5) + (v6 + v7));
    }
    for (; j + 3 < end; j += 4) {
        int s0 = slot[j], s1 = slot[j + 1], s2 = slot[j + 2], s3 = slot[j + 3];
        float v0 = __half2float(xs[(size_t)s0 * 32 + f]);
        float v1 = __half2float(xs[(size_t)s1 * 32 + f]);
        float v2 = __half2float(xs[(size_t)s2 * 32 + f]);
        float v3 = __half2float(xs[(size_t)s3 * 32 + f]);
        acc += (v0 + v1) + (v2 + v3);
    }
    for (; j < end; ++j) acc += __half2float(xs[(size_t)slot[j] * 32 + f]);
    sum1[(size_t)node * 32 + f] = acc;   // f32 padded rows for dense_mid float4 loads
}

// ---- fused dense middle: 4 waves, lane=node, f split across waves -----------
// xw2s[g] = fp16( dis[g] * (relu(dis[g]*sum1[g] @ W1 + b1) @ W2) )

__global__ __launch_bounds__(TPB) void dense_mid_kernel(
        const float* __restrict__ sum1, const float* __restrict__ dis,
        const float* __restrict__ W1t, const float* __restrict__ b1,
        const float* __restrict__ W2t, __half* __restrict__ xw2s, int n) {
    __shared__ float sh1[64][68];   // 17.4 KB, node-major padded
    __shared__ float sh2[64][33];   // 8.4 KB
    int t = threadIdx.x;
    int lane = t & 63;
    int wv = __builtin_amdgcn_readfirstlane(t >> 6);   // wave id 0..3, SGPR-uniform
    int node0 = blockIdx.x * 64;
    int g = node0 + lane;
    int gl = (g < n) ? g : (n - 1);

    // own feature row (26 useful floats of the padded 32-float row)
    float xr[28];
    {
        const float* rp = sum1 + (size_t)gl * 32;
#pragma unroll
        for (int q = 0; q < 7; ++q) {
            float4 v = *(const float4*)(rp + q * 4);
            xr[q * 4 + 0] = v.x; xr[q * 4 + 1] = v.y;
            xr[q * 4 + 2] = v.z; xr[q * 4 + 3] = v.w;
        }
    }
    float dv = dis[gl];

    // phase 1: this wave computes h1[f] for f in [wv*16, wv*16+16)
    {
        const float* Wbase = W1t + wv * 16 * 32;   // uniform
#pragma unroll
        for (int fi = 0; fi < 16; ++fi) {
            const float* Wrow = Wbase + fi * 32;   // uniform -> s_load
            float a0 = 0.0f, a1 = 0.0f;
#pragma unroll
            for (int k = 0; k < 26; k += 2) {
                a0 += xr[k] * Wrow[k];
                a1 += xr[k + 1] * Wrow[k + 1];
            }
            float h = fmaxf(dv * (a0 + a1) + b1[wv * 16 + fi], 0.0f);
            sh1[lane][wv * 16 + fi] = h;
        }
    }
    __syncthreads();

    // phase 2: read own h1 row into regs, compute f2 in [wv*8, wv*8+8)
    {
        float h1r[64];
#pragma unroll
        for (int q = 0; q < 16; ++q) {
            float4 v = *(const float4*)(&sh1[lane][q * 4]);
            h1r[q * 4 + 0] = v.x; h1r[q * 4 + 1] = v.y;
            h1r[q * 4 + 2] = v.z; h1r[q * 4 + 3] = v.w;
        }
        const float* Wbase2 = W2t + wv * 8 * 64;   // uniform
#pragma unroll
        for (int fi = 0; fi < 8; ++fi) {
            const float* Wrow = Wbase2 + fi * 64;  // uniform -> s_load
            float a0 = 0.0f, a1 = 0.0f, a2 = 0.0f, a3 = 0.0f;
#pragma unroll
            for (int k = 0; k < 64; k += 4) {
                a0 += h1r[k] * Wrow[k];
                a1 += h1r[k + 1] * Wrow[k + 1];
                a2 += h1r[k + 2] * Wrow[k + 2];
                a3 += h1r[k + 3] * Wrow[k + 3];
            }
            sh2[lane][wv * 8 + fi] = dv * (((a0 + a1) + (a2 + a3)));
        }
    }
    __syncthreads();

    // coalesced fp16 tile store
    for (int i = t; i < 64 * 32; i += TPB) {
        int r = i >> 5, ccol = i & 31;
        if (node0 + r < n)
            xw2s[(size_t)(node0 + r) * 32 + ccol] = __float2half(sh2[r][ccol]);
    }
}

// ---- layer 2 gather + bias + relu + head, fused ------------------------------

__global__ __launch_bounds__(TPB) void gather2_head_kernel(
        const __half* __restrict__ xw2s, const float* __restrict__ dis,
        const int* __restrict__ offs, const int* __restrict__ slot,
        const float* __restrict__ b2, const float* __restrict__ Wl,
        const float* __restrict__ bl, float* __restrict__ out, int n) {
    int sub = threadIdx.x >> 5;
    int f = threadIdx.x & 31;
    int node = blockIdx.x * 8 + sub;
    if (node >= n) return;
    int j = offs[node], end = offs[node + 1];
    float acc = __half2float(xw2s[(size_t)node * 32 + f]);
    for (; j + 7 < end; j += 8) {
        int s0 = slot[j], s1 = slot[j + 1], s2 = slot[j + 2], s3 = slot[j + 3];
        int s4 = slot[j + 4], s5 = slot[j + 5], s6 = slot[j + 6], s7 = slot[j + 7];
        float v0 = __half2float(xw2s[(size_t)s0 * 32 + f]);
        float v1 = __half2float(xw2s[(size_t)s1 * 32 + f]);
        float v2 = __half2float(xw2s[(size_t)s2 * 32 + f]);
        float v3 = __half2float(xw2s[(size_t)s3 * 32 + f]);
        float v4 = __half2float(xw2s[(size_t)s4 * 32 + f]);
        float v5 = __half2float(xw2s[(size_t)s5 * 32 + f]);
        float v6 = __half2float(xw2s[(size_t)s6 * 32 + f]);
        float v7 = __half2float(xw2s[(size_t)s7 * 32 + f]);
        acc += ((v0 + v1) + (v2 + v3)) + ((v4 + v5) + (v6 + v7));
    }
    for (; j + 3 < end; j += 4) {
        int s0 = slot[j], s1 = slot[j + 1], s2 = slot[j + 2], s3 = slot[j + 3];
        float v0 = __half2float(xw2s[(size_t)s0 * 32 + f]);
        float v1 = __half2float(xw2s[(size_t)s1 * 32 + f]);
        float v2 = __half2float(xw2s[(size_t)s2 * 32 + f]);
        float v3 = __half2float(xw2s[(size_t)s3 * 32 + f]);
        acc += (v0 + v1) + (v2 + v3);
    }
    for (; j < end; ++j) acc += __half2float(xw2s[(size_t)slot[j] * 32 + f]);
    float v = fmaxf(dis[node] * acc + b2[f], 0.0f);
    float c = v * Wl[f];
#pragma unroll
    for (int mm = 16; mm >= 1; mm >>= 1) c += __shfl_xor(c, mm, 32);
    if (f == 0) out[node] = c + bl[0];
}

// ---- host ------------------------------------------------------------------

extern "C" void kernel_launch(void* const* d_in, const int* in_sizes, int n_in,
                              void* d_out, int out_size, void* d_ws, size_t ws_size,
                              hipStream_t stream) {
    const float* x  = (const float*)d_in[0];
    const int*   ei = (const int*)d_in[1];
    const float* W1 = (const float*)d_in[2];
    const float* b1 = (const float*)d_in[3];
    const float* W2 = (const float*)d_in[4];
    const float* b2 = (const float*)d_in[5];
    const float* Wl = (const float*)d_in[6];
    const float* bl = (const float*)d_in[7];
    float* out = (float*)d_out;

    const int n = in_sizes[0] / 26;
    const int e = in_sizes[1] / 2;
    const int* src = ei;
    const int* dst = ei + e;

    const int nbuck = (n + NPB - 1) / NPB;   // 782 (<= NBUCK_MAX)
    const int eb    = (e + EPB - 1) / EPB;   // 147
    const int m     = nbuck * eb;            // ~115k
    const int msb   = (m + TPB - 1) / TPB;   // 450 (<= 512)

    auto align_up = [](size_t v) { return (v + 255) & ~(size_t)255; };
    char* p = (char*)d_ws;
    int*    H       = (int*)p;     p += align_up((size_t)m * 4);
    int*    SH      = (int*)p;     p += align_up((size_t)m * 4);
    int*    bsum    = (int*)p;     p += align_up(512 * 4);
    int*    sortedb = (int*)p;     p += align_up((size_t)e * 4);
    int*    slot    = (int*)p;     p += align_up((size_t)e * 4);
    float*  dis     = (float*)p;   p += align_up((size_t)n * 4);
    int*    offs    = (int*)p;     p += align_up((size_t)(n + 1) * 4);
    float*  W1t     = (float*)p;   p += align_up(64 * 32 * 4);
    float*  W2t     = (float*)p;   p += align_up(32 * 64 * 4);
    __half* xs      = (__half*)p;  p += align_up((size_t)n * 32 * 2);
    float*  sum1    = (float*)p;   p += align_up((size_t)n * 32 * 4);
    __half* xw2s    = (__half*)p;  p += align_up((size_t)n * 32 * 2);

    // 1) bucket-sorted CSR build (no global atomics) + fused prescale/transpose
    coarse_hist_kernel<<<eb, TPB, 0, stream>>>(dst, H, e, nbuck, eb);
    scan_block_kernel<<<msb, TPB, 0, stream>>>(H, SH, bsum, m);
    scan_bsum_transpose_kernel<<<1, 512, 0, stream>>>(bsum, msb, W1, W2, W1t, W2t);
    bucket_scatter_kernel<<<eb, TPB, 0, stream>>>(src, dst, SH, bsum, sortedb,
                                                  e, nbuck, eb);
    bucket_sort_fill_kernel<<<nbuck, TPB, 0, stream>>>(sortedb, SH, bsum, x, slot,
                                                       dis, offs, xs, e, n, nbuck, eb);

    // 2) layer 1 gather (fp16 table, f32 accumulate)
    gather1_kernel<<<(n + 7) / 8, TPB, 0, stream>>>(xs, offs, slot, sum1, n);

    // 3) fused dense middle (4-wave split-f, scalar-load weights, fp16 output)
    dense_mid_kernel<<<(n + 63) / 64, TPB, 0, stream>>>(sum1, dis, W1t, b1, W2t, xw2s, n);

    // 4) layer 2 gather + bias + relu + head (fused)
    gather2_head_kernel<<<(n + 7) / 8, TPB, 0, stream>>>(xw2s, dis, offs, slot,
                                                         b2, Wl, bl, out, n);
}

// Round 11
// 133.449 us; speedup vs baseline: 1.2925x; 1.0247x over previous
//
#include <hip/hip_runtime.h>
#include <hip/hip_fp16.h>

// GCN 2-layer + linear head on MI355X.
// out = relu(agg(relu(agg(X)@W1 + b1)@W2) + b2) @ Wl + bl
// agg(Y) = D^-1/2 (A+I) D^-1/2 Y  (commutes with the dense transform; layer 1
// aggregates X at 26 feats, layer 2 transforms first at 32 feats).
//
// R11 build: fixed 2048-slot region per 128-node bucket in sortedb. Each scatter
// block LDS-histograms its edge chunk, claims per-bucket ranges with ONE global
// atomicAdd per (block,bucket) (bulk, ~229k total), then scatters with LDS
// atomics. No scan pipeline, no H/SH. Per-node CSR extents stored as int2
// {start,end} (edge order within a bucket is nondeterministic across runs ->
// only fp sum order varies, well under threshold).
// Tables xs/xw2s fp16 (L2-resident random reads); fp32 accumulate.
// Dense middle: lane=node, f split across 4 waves, wave-uniform s_load weights.

#define TPB 256
#define NPB 128              // nodes per bucket (dstlow = 7 bits)
#define CAP 2048             // slots per bucket region (avg fill 1534, 13 sigma safe)
#define EPB 4096             // edges per scatter chunk
#define NBUCK_MAX 1024

// ---- scatter: LDS hist -> bulk range claim -> scatter; + W transpose (blk 0) --

__global__ __launch_bounds__(TPB) void scatter_direct_kernel(
        const int* __restrict__ src, const int* __restrict__ dst,
        int* __restrict__ bcnt, int* __restrict__ sortedb,
        const float* __restrict__ W1, const float* __restrict__ W2,
        float* __restrict__ W1t, float* __restrict__ W2t,
        int e, int nbuck) {
    __shared__ int lh[NBUCK_MAX];
    int t = threadIdx.x;
    for (int b = t; b < nbuck; b += TPB) lh[b] = 0;
    __syncthreads();
    int j0 = blockIdx.x * EPB;
    int j1 = min(e, j0 + EPB);
    for (int j = j0 + t; j < j1; j += TPB)
        atomicAdd(&lh[dst[j] >> 7], 1);              // LDS hist
    __syncthreads();
    for (int b = t; b < nbuck; b += TPB) {
        int c = lh[b];
        int base = c ? atomicAdd(&bcnt[b], c) : 0;   // bulk global claim
        lh[b] = b * CAP + base;                      // running write ptr
    }
    __syncthreads();
    for (int j = j0 + t; j < j1; j += TPB) {
        int d = dst[j];
        int s = src[j];
        int pos = atomicAdd(&lh[d >> 7], 1);         // LDS atomic only
        sortedb[pos] = (s << 7) | (d & 127);
    }
    if (blockIdx.x == 0) {
        // W1t[64][32]: W1t[f*32+k] = W1[k*64+f] (k<26; pad 0). W2t[32][64].
        for (int q = t; q < 64 * 32; q += TPB) {
            int f = q >> 5, k = q & 31;
            W1t[q] = (k < 26) ? W1[k * 64 + f] : 0.0f;
        }
        for (int q = t; q < 32 * 64; q += TPB) {
            int f = q >> 6, k = q & 63;
            W2t[q] = W2[k * 32 + f];
        }
    }
}

// ---- per bucket: degree count -> dis/extents, node-sorted slots, prescale ----

__global__ __launch_bounds__(TPB) void bucket_sort_fill_kernel(
        const int* __restrict__ sortedb, const int* __restrict__ bcnt,
        const float* __restrict__ x,
        int* __restrict__ slot, float* __restrict__ dis, int2* __restrict__ oe,
        __half* __restrict__ xs, int n, int nbuck) {
    __shared__ int c[NPB];
    __shared__ int ptr[NPB];
    __shared__ float sdis[NPB];
    int b = blockIdx.x, t = threadIdx.x;
    if (t < NPB) c[t] = 0;
    __syncthreads();
    int start = b * CAP;
    int end = start + bcnt[b];
    for (int j = start + t; j < end; j += TPB)
        atomicAdd(&c[sortedb[j] & 127], 1);
    __syncthreads();
    int mycnt = (t < NPB) ? c[t] : 0;
    // inclusive Hillis-Steele scan over 128 entries
    for (int d = 1; d < NPB; d <<= 1) {
        int v = 0;
        if (t < NPB && t >= d) v = c[t - d];
        __syncthreads();
        if (t < NPB) c[t] += v;
        __syncthreads();
    }
    if (t < NPB) {
        int excl = c[t] - mycnt;
        ptr[t] = excl;
        float dv = rsqrtf((float)mycnt + 1.0f);
        sdis[t] = dv;
        int g = b * NPB + t;
        if (g < n) {
            dis[g] = dv;
            oe[g] = make_int2(start + excl, start + excl + mycnt);
        }
    }
    __syncthreads();
    for (int j = start + t; j < end; j += TPB) {
        int w = sortedb[j];
        int pos = atomicAdd(&ptr[w & 127], 1);  // LDS atomic only
        slot[start + pos] = w >> 7;
    }
    // fused prescale (fp16 padded 64B rows)
    int base = b * NPB;
    for (int i = t; i < NPB * 32; i += TPB) {
        int r = i >> 5, lane = i & 31;
        int g = base + r;
        if (g < n)
            xs[(size_t)g * 32 + lane] = __float2half(
                (lane < 26) ? sdis[r] * x[(size_t)g * 26 + lane] : 0.0f);
    }
}

// ---- layer 1 gather: sum1[g][f] = xs[g][f] + sum_edges xs[s][f]  (fp16 -> f32) --

__global__ __launch_bounds__(TPB) void gather1_kernel(
        const __half* __restrict__ xs, const int2* __restrict__ oe,
        const int* __restrict__ slot, float* __restrict__ sum1, int n) {
    int sub = threadIdx.x >> 5;
    int f = threadIdx.x & 31;
    int node = blockIdx.x * 8 + sub;
    if (node >= n) return;
    int2 se = oe[node];
    int j = se.x, end = se.y;
    float acc = __half2float(xs[(size_t)node * 32 + f]);
    for (; j + 7 < end; j += 8) {
        int s0 = slot[j], s1 = slot[j + 1], s2 = slot[j + 2], s3 = slot[j + 3];
        int s4 = slot[j + 4], s5 = slot[j + 5], s6 = slot[j + 6], s7 = slot[j + 7];
        float v0 = __half2float(xs[(size_t)s0 * 32 + f]);
        float v1 = __half2float(xs[(size_t)s1 * 32 + f]);
        float v2 = __half2float(xs[(size_t)s2 * 32 + f]);
        float v3 = __half2float(xs[(size_t)s3 * 32 + f]);
        float v4 = __half2float(xs[(size_t)s4 * 32 + f]);
        float v5 = __half2float(xs[(size_t)s5 * 32 + f]);
        float v6 = __half2float(xs[(size_t)s6 * 32 + f]);
        float v7 = __half2float(xs[(size_t)s7 * 32 + f]);
        acc += ((v0 + v1) + (v2 + v3)) + ((v4 + v5) + (v6 + v7));
    }
    for (; j + 3 < end; j += 4) {
        int s0 = slot[j], s1 = slot[j + 1], s2 = slot[j + 2], s3 = slot[j + 3];
        float v0 = __half2float(xs[(size_t)s0 * 32 + f]);
        float v1 = __half2float(xs[(size_t)s1 * 32 + f]);
        float v2 = __half2float(xs[(size_t)s2 * 32 + f]);
        float v3 = __half2float(xs[(size_t)s3 * 32 + f]);
        acc += (v0 + v1) + (v2 + v3);
    }
    for (; j < end; ++j) acc += __half2float(xs[(size_t)slot[j] * 32 + f]);
    sum1[(size_t)node * 32 + f] = acc;   // f32 padded rows for dense_mid float4 loads
}

// ---- fused dense middle: 4 waves, lane=node, f split across waves -----------
// xw2s[g] = fp16( dis[g] * (relu(dis[g]*sum1[g] @ W1 + b1) @ W2) )

__global__ __launch_bounds__(TPB) void dense_mid_kernel(
        const float* __restrict__ sum1, const float* __restrict__ dis,
        const float* __restrict__ W1t, const float* __restrict__ b1,
        const float* __restrict__ W2t, __half* __restrict__ xw2s, int n) {
    __shared__ float sh1[64][68];   // 17.4 KB, node-major padded
    __shared__ float sh2[64][33];   // 8.4 KB
    int t = threadIdx.x;
    int lane = t & 63;
    int wv = __builtin_amdgcn_readfirstlane(t >> 6);   // wave id 0..3, SGPR-uniform
    int node0 = blockIdx.x * 64;
    int g = node0 + lane;
    int gl = (g < n) ? g : (n - 1);

    float xr[28];
    {
        const float* rp = sum1 + (size_t)gl * 32;
#pragma unroll
        for (int q = 0; q < 7; ++q) {
            float4 v = *(const float4*)(rp + q * 4);
            xr[q * 4 + 0] = v.x; xr[q * 4 + 1] = v.y;
            xr[q * 4 + 2] = v.z; xr[q * 4 + 3] = v.w;
        }
    }
    float dv = dis[gl];

    {
        const float* Wbase = W1t + wv * 16 * 32;   // uniform
#pragma unroll
        for (int fi = 0; fi < 16; ++fi) {
            const float* Wrow = Wbase + fi * 32;   // uniform -> s_load
            float a0 = 0.0f, a1 = 0.0f;
#pragma unroll
            for (int k = 0; k < 26; k += 2) {
                a0 += xr[k] * Wrow[k];
                a1 += xr[k + 1] * Wrow[k + 1];
            }
            float h = fmaxf(dv * (a0 + a1) + b1[wv * 16 + fi], 0.0f);
            sh1[lane][wv * 16 + fi] = h;
        }
    }
    __syncthreads();

    {
        float h1r[64];
#pragma unroll
        for (int q = 0; q < 16; ++q) {
            float4 v = *(const float4*)(&sh1[lane][q * 4]);
            h1r[q * 4 + 0] = v.x; h1r[q * 4 + 1] = v.y;
            h1r[q * 4 + 2] = v.z; h1r[q * 4 + 3] = v.w;
        }
        const float* Wbase2 = W2t + wv * 8 * 64;   // uniform
#pragma unroll
        for (int fi = 0; fi < 8; ++fi) {
            const float* Wrow = Wbase2 + fi * 64;  // uniform -> s_load
            float a0 = 0.0f, a1 = 0.0f, a2 = 0.0f, a3 = 0.0f;
#pragma unroll
            for (int k = 0; k < 64; k += 4) {
                a0 += h1r[k] * Wrow[k];
                a1 += h1r[k + 1] * Wrow[k + 1];
                a2 += h1r[k + 2] * Wrow[k + 2];
                a3 += h1r[k + 3] * Wrow[k + 3];
            }
            sh2[lane][wv * 8 + fi] = dv * (((a0 + a1) + (a2 + a3)));
        }
    }
    __syncthreads();

    for (int i = t; i < 64 * 32; i += TPB) {
        int r = i >> 5, ccol = i & 31;
        if (node0 + r < n)
            xw2s[(size_t)(node0 + r) * 32 + ccol] = __float2half(sh2[r][ccol]);
    }
}

// ---- layer 2 gather + bias + relu + head, fused ------------------------------

__global__ __launch_bounds__(TPB) void gather2_head_kernel(
        const __half* __restrict__ xw2s, const float* __restrict__ dis,
        const int2* __restrict__ oe, const int* __restrict__ slot,
        const float* __restrict__ b2, const float* __restrict__ Wl,
        const float* __restrict__ bl, float* __restrict__ out, int n) {
    int sub = threadIdx.x >> 5;
    int f = threadIdx.x & 31;
    int node = blockIdx.x * 8 + sub;
    if (node >= n) return;
    int2 se = oe[node];
    int j = se.x, end = se.y;
    float acc = __half2float(xw2s[(size_t)node * 32 + f]);
    for (; j + 7 < end; j += 8) {
        int s0 = slot[j], s1 = slot[j + 1], s2 = slot[j + 2], s3 = slot[j + 3];
        int s4 = slot[j + 4], s5 = slot[j + 5], s6 = slot[j + 6], s7 = slot[j + 7];
        float v0 = __half2float(xw2s[(size_t)s0 * 32 + f]);
        float v1 = __half2float(xw2s[(size_t)s1 * 32 + f]);
        float v2 = __half2float(xw2s[(size_t)s2 * 32 + f]);
        float v3 = __half2float(xw2s[(size_t)s3 * 32 + f]);
        float v4 = __half2float(xw2s[(size_t)s4 * 32 + f]);
        float v5 = __half2float(xw2s[(size_t)s5 * 32 + f]);
        float v6 = __half2float(xw2s[(size_t)s6 * 32 + f]);
        float v7 = __half2float(xw2s[(size_t)s7 * 32 + f]);
        acc += ((v0 + v1) + (v2 + v3)) + ((v4 + v5) + (v6 + v7));
    }
    for (; j + 3 < end; j += 4) {
        int s0 = slot[j], s1 = slot[j + 1], s2 = slot[j + 2], s3 = slot[j + 3];
        float v0 = __half2float(xw2s[(size_t)s0 * 32 + f]);
        float v1 = __half2float(xw2s[(size_t)s1 * 32 + f]);
        float v2 = __half2float(xw2s[(size_t)s2 * 32 + f]);
        float v3 = __half2float(xw2s[(size_t)s3 * 32 + f]);
        acc += (v0 + v1) + (v2 + v3);
    }
    for (; j < end; ++j) acc += __half2float(xw2s[(size_t)slot[j] * 32 + f]);
    float v = fmaxf(dis[node] * acc + b2[f], 0.0f);
    float c = v * Wl[f];
#pragma unroll
    for (int mm = 16; mm >= 1; mm >>= 1) c += __shfl_xor(c, mm, 32);
    if (f == 0) out[node] = c + bl[0];
}

// ---- host ------------------------------------------------------------------

extern "C" void kernel_launch(void* const* d_in, const int* in_sizes, int n_in,
                              void* d_out, int out_size, void* d_ws, size_t ws_size,
                              hipStream_t stream) {
    const float* x  = (const float*)d_in[0];
    const int*   ei = (const int*)d_in[1];
    const float* W1 = (const float*)d_in[2];
    const float* b1 = (const float*)d_in[3];
    const float* W2 = (const float*)d_in[4];
    const float* b2 = (const float*)d_in[5];
    const float* Wl = (const float*)d_in[6];
    const float* bl = (const float*)d_in[7];
    float* out = (float*)d_out;

    const int n = in_sizes[0] / 26;
    const int e = in_sizes[1] / 2;
    const int* src = ei;
    const int* dst = ei + e;

    const int nbuck = (n + NPB - 1) / NPB;   // 782 (<= NBUCK_MAX)
    const int eb    = (e + EPB - 1) / EPB;   // 293 scatter chunks

    auto align_up = [](size_t v) { return (v + 255) & ~(size_t)255; };
    char* p = (char*)d_ws;
    int*    bcnt    = (int*)p;     p += align_up((size_t)nbuck * 4);
    int*    sortedb = (int*)p;     p += align_up(((size_t)nbuck * CAP + 4096) * 4);
    int*    slot    = (int*)p;     p += align_up(((size_t)nbuck * CAP + 4096) * 4);
    float*  dis     = (float*)p;   p += align_up((size_t)n * 4);
    int2*   oe      = (int2*)p;    p += align_up((size_t)n * 8);
    float*  W1t     = (float*)p;   p += align_up(64 * 32 * 4);
    float*  W2t     = (float*)p;   p += align_up(32 * 64 * 4);
    __half* xs      = (__half*)p;  p += align_up((size_t)n * 32 * 2);
    float*  sum1    = (float*)p;   p += align_up((size_t)n * 32 * 4);
    __half* xw2s    = (__half*)p;  p += align_up((size_t)n * 32 * 2);

    // 1) build: zero bucket counters, scatter with bulk range claiming
    hipMemsetAsync(bcnt, 0, (size_t)nbuck * 4, stream);
    scatter_direct_kernel<<<eb, TPB, 0, stream>>>(src, dst, bcnt, sortedb,
                                                  W1, W2, W1t, W2t, e, nbuck);
    bucket_sort_fill_kernel<<<nbuck, TPB, 0, stream>>>(sortedb, bcnt, x, slot,
                                                       dis, oe, xs, n, nbuck);

    // 2) layer 1 gather (fp16 table, f32 accumulate)
    gather1_kernel<<<(n + 7) / 8, TPB, 0, stream>>>(xs, oe, slot, sum1, n);

    // 3) fused dense middle (4-wave split-f, scalar-load weights, fp16 output)
    dense_mid_kernel<<<(n + 63) / 64, TPB, 0, stream>>>(sum1, dis, W1t, b1, W2t, xw2s, n);

    // 4) layer 2 gather + bias + relu + head (fused)
    gather2_head_kernel<<<(n + 7) / 8, TPB, 0, stream>>>(xw2s, dis, oe, slot,
                                                         b2, Wl, bl, out, n);
}

// Round 12
// 127.335 us; speedup vs baseline: 1.3545x; 1.0480x over previous
//
#include <hip/hip_runtime.h>
#include <hip/hip_fp16.h>

// GCN 2-layer + linear head on MI355X.
// out = relu(agg(relu(agg(X)@W1 + b1)@W2) + b2) @ Wl + bl
// agg(Y) = D^-1/2 (A+I) D^-1/2 Y  (commutes with the dense transform; layer 1
// aggregates X at 26 feats, layer 2 transforms first at 32 feats).
//
// Build: fixed 2048-slot region per 128-node bucket; per-chunk LDS hist -> one
// global atomicAdd per (chunk,bucket) range claim -> LDS-atomic scatter. Then
// per-bucket degree/extents/node-sort/prescale. Tables xs/xw2s fp16.
// Dense middle (R12): MFMA. Per wave: 16-node tile; layer1 = 4x
// mfma_f32_16x16x32_f16 (K=32 covers padded 26 exactly), h1 -> per-wave LDS
// tile (fp16, no barriers), layer2 = 4 MFMAs (2 K-steps x 2 f-tiles).
// Fragment maps (gfx950, HW-verified): A/B non-K index = lane&15, K-slice =
// (lane>>4)*8; C/D col=lane&15, row=(lane>>4)*4+reg.

#define TPB 256
#define NPB 128              // nodes per bucket (dstlow = 7 bits)
#define CAP 2048             // slots per bucket region (avg fill 1534, 13 sigma safe)
#define EPB 4096             // edges per scatter chunk
#define NBUCK_MAX 1024

typedef _Float16 half8 __attribute__((ext_vector_type(8)));
typedef float floatx4 __attribute__((ext_vector_type(4)));

// ---- scatter: LDS hist -> bulk range claim -> scatter; + W transpose (blk 0) --

__global__ __launch_bounds__(TPB) void scatter_direct_kernel(
        const int* __restrict__ src, const int* __restrict__ dst,
        int* __restrict__ bcnt, int* __restrict__ sortedb,
        const float* __restrict__ W1, const float* __restrict__ W2,
        float* __restrict__ W1t, float* __restrict__ W2t,
        int e, int nbuck) {
    __shared__ int lh[NBUCK_MAX];
    int t = threadIdx.x;
    for (int b = t; b < nbuck; b += TPB) lh[b] = 0;
    __syncthreads();
    int j0 = blockIdx.x * EPB;
    int j1 = min(e, j0 + EPB);
    for (int j = j0 + t; j < j1; j += TPB)
        atomicAdd(&lh[dst[j] >> 7], 1);              // LDS hist
    __syncthreads();
    for (int b = t; b < nbuck; b += TPB) {
        int c = lh[b];
        int base = c ? atomicAdd(&bcnt[b], c) : 0;   // bulk global claim
        lh[b] = b * CAP + base;                      // running write ptr
    }
    __syncthreads();
    for (int j = j0 + t; j < j1; j += TPB) {
        int d = dst[j];
        int s = src[j];
        int pos = atomicAdd(&lh[d >> 7], 1);         // LDS atomic only
        sortedb[pos] = (s << 7) | (d & 127);
    }
    if (blockIdx.x == 0) {
        // W1t[64][32]: W1t[f*32+k] = W1[k*64+f] (k<26; pad 0). W2t[32][64].
        for (int q = t; q < 64 * 32; q += TPB) {
            int f = q >> 5, k = q & 31;
            W1t[q] = (k < 26) ? W1[k * 64 + f] : 0.0f;
        }
        for (int q = t; q < 32 * 64; q += TPB) {
            int f = q >> 6, k = q & 63;
            W2t[q] = W2[k * 32 + f];
        }
    }
}

// ---- per bucket: degree count -> dis/extents, node-sorted slots, prescale ----

__global__ __launch_bounds__(TPB) void bucket_sort_fill_kernel(
        const int* __restrict__ sortedb, const int* __restrict__ bcnt,
        const float* __restrict__ x,
        int* __restrict__ slot, float* __restrict__ dis, int2* __restrict__ oe,
        __half* __restrict__ xs, int n, int nbuck) {
    __shared__ int c[NPB];
    __shared__ int ptr[NPB];
    __shared__ float sdis[NPB];
    int b = blockIdx.x, t = threadIdx.x;
    if (t < NPB) c[t] = 0;
    __syncthreads();
    int start = b * CAP;
    int end = start + bcnt[b];
    for (int j = start + t; j < end; j += TPB)
        atomicAdd(&c[sortedb[j] & 127], 1);
    __syncthreads();
    int mycnt = (t < NPB) ? c[t] : 0;
    // inclusive Hillis-Steele scan over 128 entries
    for (int d = 1; d < NPB; d <<= 1) {
        int v = 0;
        if (t < NPB && t >= d) v = c[t - d];
        __syncthreads();
        if (t < NPB) c[t] += v;
        __syncthreads();
    }
    if (t < NPB) {
        int excl = c[t] - mycnt;
        ptr[t] = excl;
        float dv = rsqrtf((float)mycnt + 1.0f);
        sdis[t] = dv;
        int g = b * NPB + t;
        if (g < n) {
            dis[g] = dv;
            oe[g] = make_int2(start + excl, start + excl + mycnt);
        }
    }
    __syncthreads();
    for (int j = start + t; j < end; j += TPB) {
        int w = sortedb[j];
        int pos = atomicAdd(&ptr[w & 127], 1);  // LDS atomic only
        slot[start + pos] = w >> 7;
    }
    // fused prescale (fp16 padded 64B rows)
    int base = b * NPB;
    for (int i = t; i < NPB * 32; i += TPB) {
        int r = i >> 5, lane = i & 31;
        int g = base + r;
        if (g < n)
            xs[(size_t)g * 32 + lane] = __float2half(
                (lane < 26) ? sdis[r] * x[(size_t)g * 26 + lane] : 0.0f);
    }
}

// ---- layer 1 gather: sum1[g][f] = xs[g][f] + sum_edges xs[s][f]  (fp16 -> f32) --

__global__ __launch_bounds__(TPB) void gather1_kernel(
        const __half* __restrict__ xs, const int2* __restrict__ oe,
        const int* __restrict__ slot, float* __restrict__ sum1, int n) {
    int sub = threadIdx.x >> 5;
    int f = threadIdx.x & 31;
    int node = blockIdx.x * 8 + sub;
    if (node >= n) return;
    int2 se = oe[node];
    int j = se.x, end = se.y;
    float acc = __half2float(xs[(size_t)node * 32 + f]);
    for (; j + 7 < end; j += 8) {
        int s0 = slot[j], s1 = slot[j + 1], s2 = slot[j + 2], s3 = slot[j + 3];
        int s4 = slot[j + 4], s5 = slot[j + 5], s6 = slot[j + 6], s7 = slot[j + 7];
        float v0 = __half2float(xs[(size_t)s0 * 32 + f]);
        float v1 = __half2float(xs[(size_t)s1 * 32 + f]);
        float v2 = __half2float(xs[(size_t)s2 * 32 + f]);
        float v3 = __half2float(xs[(size_t)s3 * 32 + f]);
        float v4 = __half2float(xs[(size_t)s4 * 32 + f]);
        float v5 = __half2float(xs[(size_t)s5 * 32 + f]);
        float v6 = __half2float(xs[(size_t)s6 * 32 + f]);
        float v7 = __half2float(xs[(size_t)s7 * 32 + f]);
        acc += ((v0 + v1) + (v2 + v3)) + ((v4 + v5) + (v6 + v7));
    }
    for (; j + 3 < end; j += 4) {
        int s0 = slot[j], s1 = slot[j + 1], s2 = slot[j + 2], s3 = slot[j + 3];
        float v0 = __half2float(xs[(size_t)s0 * 32 + f]);
        float v1 = __half2float(xs[(size_t)s1 * 32 + f]);
        float v2 = __half2float(xs[(size_t)s2 * 32 + f]);
        float v3 = __half2float(xs[(size_t)s3 * 32 + f]);
        acc += (v0 + v1) + (v2 + v3);
    }
    for (; j < end; ++j) acc += __half2float(xs[(size_t)slot[j] * 32 + f]);
    sum1[(size_t)node * 32 + f] = acc;   // f32 padded rows
}

// ---- MFMA dense middle ------------------------------------------------------
// xw2s[g] = fp16( dis[g] * (relu(dis[g]*sum1[g] @ W1 + b1) @ W2) )
// Per wave: 16-node tile, barrier-free (per-wave LDS sub-tiles).

__global__ __launch_bounds__(TPB) void dense_mid_kernel(
        const float* __restrict__ sum1, const float* __restrict__ dis,
        const float* __restrict__ W1t, const float* __restrict__ b1,
        const float* __restrict__ W2t, __half* __restrict__ xw2s, int n) {
    __shared__ _Float16 shh[4][16][72];   // h1: 16 nodes x 64 f (+pad 8); rows 144B (16B-mult)
    __shared__ _Float16 sho[4][16][40];   // out: 16 nodes x 32 f2 (+pad 8); rows 80B (16B-mult)
    int t = threadIdx.x;
    int w = t >> 6, l = t & 63;
    int node0 = blockIdx.x * 64 + w * 16;
    int lm = l & 15;           // A/B non-K index
    int lk = l >> 4;           // K-slice id 0..3

    // A1 fragment: node row lm, k-slice lk*8..+8 (fp32 -> fp16)
    int nodeA = node0 + lm; if (nodeA >= n) nodeA = n - 1;
    const float* ap = sum1 + (size_t)nodeA * 32 + lk * 8;
    float4 av0 = *(const float4*)ap;
    float4 av1 = *(const float4*)(ap + 4);
    half8 a1;
    a1[0] = (_Float16)av0.x; a1[1] = (_Float16)av0.y;
    a1[2] = (_Float16)av0.z; a1[3] = (_Float16)av0.w;
    a1[4] = (_Float16)av1.x; a1[5] = (_Float16)av1.y;
    a1[6] = (_Float16)av1.z; a1[7] = (_Float16)av1.w;

    // dis for the 4 C-rows this lane maps to: node = node0 + lk*4 + r
    float dvv[4];
#pragma unroll
    for (int r = 0; r < 4; ++r) {
        int nd = node0 + lk * 4 + r;
        dvv[r] = dis[nd < n ? nd : (n - 1)];
    }

    // ---- layer 1: 4 f-tiles of 16
#pragma unroll
    for (int T = 0; T < 4; ++T) {
        const float* bp = W1t + (size_t)(T * 16 + lm) * 32 + lk * 8;
        float4 bv0 = *(const float4*)bp;
        float4 bv1 = *(const float4*)(bp + 4);
        half8 bf;
        bf[0] = (_Float16)bv0.x; bf[1] = (_Float16)bv0.y;
        bf[2] = (_Float16)bv0.z; bf[3] = (_Float16)bv0.w;
        bf[4] = (_Float16)bv1.x; bf[5] = (_Float16)bv1.y;
        bf[6] = (_Float16)bv1.z; bf[7] = (_Float16)bv1.w;
        floatx4 c = {0.0f, 0.0f, 0.0f, 0.0f};
        c = __builtin_amdgcn_mfma_f32_16x16x32_f16(a1, bf, c, 0, 0, 0);
        float bias = b1[T * 16 + lm];
#pragma unroll
        for (int r = 0; r < 4; ++r) {
            float h = fmaxf(dvv[r] * c[r] + bias, 0.0f);
            shh[w][lk * 4 + r][T * 16 + lm] = (_Float16)h;
        }
    }

    // ---- layer 2: A2 from per-wave LDS tile (node=lm), 2 K-steps x 2 f-tiles
    half8 a2k0 = *(const half8*)&shh[w][lm][lk * 8];
    half8 a2k1 = *(const half8*)&shh[w][lm][32 + lk * 8];
#pragma unroll
    for (int T = 0; T < 2; ++T) {
        const float* bp0 = W2t + (size_t)(T * 16 + lm) * 64 + lk * 8;
        const float* bp1 = bp0 + 32;
        float4 c0 = *(const float4*)bp0;
        float4 c1 = *(const float4*)(bp0 + 4);
        float4 c2 = *(const float4*)bp1;
        float4 c3 = *(const float4*)(bp1 + 4);
        half8 bf0, bf1;
        bf0[0] = (_Float16)c0.x; bf0[1] = (_Float16)c0.y;
        bf0[2] = (_Float16)c0.z; bf0[3] = (_Float16)c0.w;
        bf0[4] = (_Float16)c1.x; bf0[5] = (_Float16)c1.y;
        bf0[6] = (_Float16)c1.z; bf0[7] = (_Float16)c1.w;
        bf1[0] = (_Float16)c2.x; bf1[1] = (_Float16)c2.y;
        bf1[2] = (_Float16)c2.z; bf1[3] = (_Float16)c2.w;
        bf1[4] = (_Float16)c3.x; bf1[5] = (_Float16)c3.y;
        bf1[6] = (_Float16)c3.z; bf1[7] = (_Float16)c3.w;
        floatx4 acc = {0.0f, 0.0f, 0.0f, 0.0f};
        acc = __builtin_amdgcn_mfma_f32_16x16x32_f16(a2k0, bf0, acc, 0, 0, 0);
        acc = __builtin_amdgcn_mfma_f32_16x16x32_f16(a2k1, bf1, acc, 0, 0, 0);
#pragma unroll
        for (int r = 0; r < 4; ++r)
            sho[w][lk * 4 + r][T * 16 + lm] = (_Float16)(dvv[r] * acc[r]);
    }

    // coalesced store: lane -> node_local l>>2, f2-chunk (l&3)*8
    int nl = l >> 2, fc = (l & 3) * 8;
    int gnode = node0 + nl;
    if (gnode < n) {
        half8 v = *(const half8*)&sho[w][nl][fc];
        *(half8*)((_Float16*)xw2s + (size_t)gnode * 32 + fc) = v;
    }
}

// ---- layer 2 gather + bias + relu + head, fused ------------------------------

__global__ __launch_bounds__(TPB) void gather2_head_kernel(
        const __half* __restrict__ xw2s, const float* __restrict__ dis,
        const int2* __restrict__ oe, const int* __restrict__ slot,
        const float* __restrict__ b2, const float* __restrict__ Wl,
        const float* __restrict__ bl, float* __restrict__ out, int n) {
    int sub = threadIdx.x >> 5;
    int f = threadIdx.x & 31;
    int node = blockIdx.x * 8 + sub;
    if (node >= n) return;
    int2 se = oe[node];
    int j = se.x, end = se.y;
    float acc = __half2float(xw2s[(size_t)node * 32 + f]);
    for (; j + 7 < end; j += 8) {
        int s0 = slot[j], s1 = slot[j + 1], s2 = slot[j + 2], s3 = slot[j + 3];
        int s4 = slot[j + 4], s5 = slot[j + 5], s6 = slot[j + 6], s7 = slot[j + 7];
        float v0 = __half2float(xw2s[(size_t)s0 * 32 + f]);
        float v1 = __half2float(xw2s[(size_t)s1 * 32 + f]);
        float v2 = __half2float(xw2s[(size_t)s2 * 32 + f]);
        float v3 = __half2float(xw2s[(size_t)s3 * 32 + f]);
        float v4 = __half2float(xw2s[(size_t)s4 * 32 + f]);
        float v5 = __half2float(xw2s[(size_t)s5 * 32 + f]);
        float v6 = __half2float(xw2s[(size_t)s6 * 32 + f]);
        float v7 = __half2float(xw2s[(size_t)s7 * 32 + f]);
        acc += ((v0 + v1) + (v2 + v3)) + ((v4 + v5) + (v6 + v7));
    }
    for (; j + 3 < end; j += 4) {
        int s0 = slot[j], s1 = slot[j + 1], s2 = slot[j + 2], s3 = slot[j + 3];
        float v0 = __half2float(xw2s[(size_t)s0 * 32 + f]);
        float v1 = __half2float(xw2s[(size_t)s1 * 32 + f]);
        float v2 = __half2float(xw2s[(size_t)s2 * 32 + f]);
        float v3 = __half2float(xw2s[(size_t)s3 * 32 + f]);
        acc += (v0 + v1) + (v2 + v3);
    }
    for (; j < end; ++j) acc += __half2float(xw2s[(size_t)slot[j] * 32 + f]);
    float v = fmaxf(dis[node] * acc + b2[f], 0.0f);
    float c = v * Wl[f];
#pragma unroll
    for (int mm = 16; mm >= 1; mm >>= 1) c += __shfl_xor(c, mm, 32);
    if (f == 0) out[node] = c + bl[0];
}

// ---- host ------------------------------------------------------------------

extern "C" void kernel_launch(void* const* d_in, const int* in_sizes, int n_in,
                              void* d_out, int out_size, void* d_ws, size_t ws_size,
                              hipStream_t stream) {
    const float* x  = (const float*)d_in[0];
    const int*   ei = (const int*)d_in[1];
    const float* W1 = (const float*)d_in[2];
    const float* b1 = (const float*)d_in[3];
    const float* W2 = (const float*)d_in[4];
    const float* b2 = (const float*)d_in[5];
    const float* Wl = (const float*)d_in[6];
    const float* bl = (const float*)d_in[7];
    float* out = (float*)d_out;

    const int n = in_sizes[0] / 26;
    const int e = in_sizes[1] / 2;
    const int* src = ei;
    const int* dst = ei + e;

    const int nbuck = (n + NPB - 1) / NPB;   // 782 (<= NBUCK_MAX)
    const int eb    = (e + EPB - 1) / EPB;   // 293 scatter chunks

    auto align_up = [](size_t v) { return (v + 255) & ~(size_t)255; };
    char* p = (char*)d_ws;
    int*    bcnt    = (int*)p;     p += align_up((size_t)nbuck * 4);
    int*    sortedb = (int*)p;     p += align_up(((size_t)nbuck * CAP + 4096) * 4);
    int*    slot    = (int*)p;     p += align_up(((size_t)nbuck * CAP + 4096) * 4);
    float*  dis     = (float*)p;   p += align_up((size_t)n * 4);
    int2*   oe      = (int2*)p;    p += align_up((size_t)n * 8);
    float*  W1t     = (float*)p;   p += align_up(64 * 32 * 4);
    float*  W2t     = (float*)p;   p += align_up(32 * 64 * 4);
    __half* xs      = (__half*)p;  p += align_up((size_t)n * 32 * 2);
    float*  sum1    = (float*)p;   p += align_up((size_t)n * 32 * 4);
    __half* xw2s    = (__half*)p;  p += align_up((size_t)n * 32 * 2);

    // 1) build: zero bucket counters, scatter with bulk range claiming
    hipMemsetAsync(bcnt, 0, (size_t)nbuck * 4, stream);
    scatter_direct_kernel<<<eb, TPB, 0, stream>>>(src, dst, bcnt, sortedb,
                                                  W1, W2, W1t, W2t, e, nbuck);
    bucket_sort_fill_kernel<<<nbuck, TPB, 0, stream>>>(sortedb, bcnt, x, slot,
                                                       dis, oe, xs, n, nbuck);

    // 2) layer 1 gather (fp16 table, f32 accumulate)
    gather1_kernel<<<(n + 7) / 8, TPB, 0, stream>>>(xs, oe, slot, sum1, n);

    // 3) MFMA dense middle
    dense_mid_kernel<<<(n + 63) / 64, TPB, 0, stream>>>(sum1, dis, W1t, b1, W2t, xw2s, n);

    // 4) layer 2 gather + bias + relu + head (fused)
    gather2_head_kernel<<<(n + 7) / 8, TPB, 0, stream>>>(xw2s, dis, oe, slot,
                                                         b2, Wl, bl, out, n);
}

// Round 13
// 125.092 us; speedup vs baseline: 1.3788x; 1.0179x over previous
//
#include <hip/hip_runtime.h>
#include <hip/hip_fp16.h>

// GCN 2-layer + linear head on MI355X.
// out = relu(agg(relu(agg(X)@W1 + b1)@W2) + b2) @ Wl + bl
// agg(Y) = D^-1/2 (A+I) D^-1/2 Y  (commutes with the dense transform; layer 1
// aggregates X at 26 feats, layer 2 transforms first at 32 feats).
//
// Build: fixed 2048-slot region per 128-node bucket; per-chunk LDS hist -> one
// global atomicAdd per (chunk,bucket) range claim -> LDS-atomic scatter. Then
// per-bucket degree/extents/node-sort/prescale (xs fp16, padded 64B rows).
// R13: gather1 FUSED with the MFMA dense middle — gather accumulates f32 and
// stores fp16 into an LDS tile (same rounding point as R12); MFMA phase reads
// A-fragments from LDS. sum1 round-trip and one launch gap deleted.
// Fragment maps (gfx950, HW-verified): A/B non-K index = lane&15, K-slice =
// (lane>>4)*8; C/D col=lane&15, row=(lane>>4)*4+reg.

#define TPB 256
#define NPB 128              // nodes per bucket (dstlow = 7 bits)
#define CAP 2048             // slots per bucket region (avg fill 1534, 13 sigma safe)
#define EPB 4096             // edges per scatter chunk
#define NBUCK_MAX 1024

typedef _Float16 half8 __attribute__((ext_vector_type(8)));
typedef float floatx4 __attribute__((ext_vector_type(4)));

// ---- scatter: LDS hist -> bulk range claim -> scatter; + W transpose (blk 0) --

__global__ __launch_bounds__(TPB) void scatter_direct_kernel(
        const int* __restrict__ src, const int* __restrict__ dst,
        int* __restrict__ bcnt, int* __restrict__ sortedb,
        const float* __restrict__ W1, const float* __restrict__ W2,
        float* __restrict__ W1t, float* __restrict__ W2t,
        int e, int nbuck) {
    __shared__ int lh[NBUCK_MAX];
    int t = threadIdx.x;
    for (int b = t; b < nbuck; b += TPB) lh[b] = 0;
    __syncthreads();
    int j0 = blockIdx.x * EPB;
    int j1 = min(e, j0 + EPB);
    for (int j = j0 + t; j < j1; j += TPB)
        atomicAdd(&lh[dst[j] >> 7], 1);              // LDS hist
    __syncthreads();
    for (int b = t; b < nbuck; b += TPB) {
        int c = lh[b];
        int base = c ? atomicAdd(&bcnt[b], c) : 0;   // bulk global claim
        lh[b] = b * CAP + base;                      // running write ptr
    }
    __syncthreads();
    for (int j = j0 + t; j < j1; j += TPB) {
        int d = dst[j];
        int s = src[j];
        int pos = atomicAdd(&lh[d >> 7], 1);         // LDS atomic only
        sortedb[pos] = (s << 7) | (d & 127);
    }
    if (blockIdx.x == 0) {
        // W1t[64][32]: W1t[f*32+k] = W1[k*64+f] (k<26; pad 0). W2t[32][64].
        for (int q = t; q < 64 * 32; q += TPB) {
            int f = q >> 5, k = q & 31;
            W1t[q] = (k < 26) ? W1[k * 64 + f] : 0.0f;
        }
        for (int q = t; q < 32 * 64; q += TPB) {
            int f = q >> 6, k = q & 63;
            W2t[q] = W2[k * 32 + f];
        }
    }
}

// ---- per bucket: degree count -> dis/extents, node-sorted slots, prescale ----

__global__ __launch_bounds__(TPB) void bucket_sort_fill_kernel(
        const int* __restrict__ sortedb, const int* __restrict__ bcnt,
        const float* __restrict__ x,
        int* __restrict__ slot, float* __restrict__ dis, int2* __restrict__ oe,
        __half* __restrict__ xs, int n, int nbuck) {
    __shared__ int c[NPB];
    __shared__ int ptr[NPB];
    __shared__ float sdis[NPB];
    int b = blockIdx.x, t = threadIdx.x;
    if (t < NPB) c[t] = 0;
    __syncthreads();
    int start = b * CAP;
    int end = start + bcnt[b];
    for (int j = start + t; j < end; j += TPB)
        atomicAdd(&c[sortedb[j] & 127], 1);
    __syncthreads();
    int mycnt = (t < NPB) ? c[t] : 0;
    // inclusive Hillis-Steele scan over 128 entries
    for (int d = 1; d < NPB; d <<= 1) {
        int v = 0;
        if (t < NPB && t >= d) v = c[t - d];
        __syncthreads();
        if (t < NPB) c[t] += v;
        __syncthreads();
    }
    if (t < NPB) {
        int excl = c[t] - mycnt;
        ptr[t] = excl;
        float dv = rsqrtf((float)mycnt + 1.0f);
        sdis[t] = dv;
        int g = b * NPB + t;
        if (g < n) {
            dis[g] = dv;
            oe[g] = make_int2(start + excl, start + excl + mycnt);
        }
    }
    __syncthreads();
    for (int j = start + t; j < end; j += TPB) {
        int w = sortedb[j];
        int pos = atomicAdd(&ptr[w & 127], 1);  // LDS atomic only
        slot[start + pos] = w >> 7;
    }
    // fused prescale (fp16 padded 64B rows)
    int base = b * NPB;
    for (int i = t; i < NPB * 32; i += TPB) {
        int r = i >> 5, lane = i & 31;
        int g = base + r;
        if (g < n)
            xs[(size_t)g * 32 + lane] = __float2half(
                (lane < 26) ? sdis[r] * x[(size_t)g * 26 + lane] : 0.0f);
    }
}

// ---- fused gather1 + MFMA dense middle --------------------------------------
// Phase A: 8x 32-lane groups gather 8 consecutive nodes each (f32 acc) ->
//          fp16 LDS tile ssum[64][40].
// Phase B: per-wave 16-node tile; layer1 = 4x mfma_f32_16x16x32_f16 (A from
//          LDS), h1 -> per-wave LDS (no barrier), layer2 = 4 MFMAs; fp16 store.

__global__ __launch_bounds__(TPB) void gather1_dense_kernel(
        const __half* __restrict__ xs, const int2* __restrict__ oe,
        const int* __restrict__ slot, const float* __restrict__ dis,
        const float* __restrict__ W1t, const float* __restrict__ b1,
        const float* __restrict__ W2t, __half* __restrict__ xw2s, int n) {
    __shared__ _Float16 ssum[64][40];     // agg(X) tile: 64 nodes x 32 f (+8 pad) = 5.1 KB
    __shared__ _Float16 shh[4][16][72];   // h1: per-wave 16x64 (+8 pad) = 9.2 KB
    __shared__ _Float16 sho[4][16][40];   // out: per-wave 16x32 (+8 pad) = 5.1 KB
    int t = threadIdx.x;
    int node0 = blockIdx.x * 64;

    // ---- phase A: gather
    {
        int g = t >> 5;
        int f = t & 31;
#pragma unroll 1
        for (int i = 0; i < 8; ++i) {
            int nl = g * 8 + i;
            int node = node0 + nl;
            float acc = 0.0f;
            if (node < n) {
                int2 se = oe[node];
                int j = se.x, end = se.y;
                acc = __half2float(xs[(size_t)node * 32 + f]);
                for (; j + 7 < end; j += 8) {
                    int s0 = slot[j], s1 = slot[j + 1], s2 = slot[j + 2], s3 = slot[j + 3];
                    int s4 = slot[j + 4], s5 = slot[j + 5], s6 = slot[j + 6], s7 = slot[j + 7];
                    float v0 = __half2float(xs[(size_t)s0 * 32 + f]);
                    float v1 = __half2float(xs[(size_t)s1 * 32 + f]);
                    float v2 = __half2float(xs[(size_t)s2 * 32 + f]);
                    float v3 = __half2float(xs[(size_t)s3 * 32 + f]);
                    float v4 = __half2float(xs[(size_t)s4 * 32 + f]);
                    float v5 = __half2float(xs[(size_t)s5 * 32 + f]);
                    float v6 = __half2float(xs[(size_t)s6 * 32 + f]);
                    float v7 = __half2float(xs[(size_t)s7 * 32 + f]);
                    acc += ((v0 + v1) + (v2 + v3)) + ((v4 + v5) + (v6 + v7));
                }
                for (; j + 3 < end; j += 4) {
                    int s0 = slot[j], s1 = slot[j + 1], s2 = slot[j + 2], s3 = slot[j + 3];
                    float v0 = __half2float(xs[(size_t)s0 * 32 + f]);
                    float v1 = __half2float(xs[(size_t)s1 * 32 + f]);
                    float v2 = __half2float(xs[(size_t)s2 * 32 + f]);
                    float v3 = __half2float(xs[(size_t)s3 * 32 + f]);
                    acc += (v0 + v1) + (v2 + v3);
                }
                for (; j < end; ++j) acc += __half2float(xs[(size_t)slot[j] * 32 + f]);
            }
            ssum[nl][f] = (_Float16)acc;
        }
    }
    __syncthreads();

    // ---- phase B: MFMA dense middle
    int w = t >> 6, l = t & 63;
    int tnode0 = node0 + w * 16;
    int lm = l & 15;           // A/B non-K index
    int lk = l >> 4;           // K-slice id 0..3

    // A1 fragment straight from LDS (fp16)
    half8 a1 = *(const half8*)&ssum[w * 16 + lm][lk * 8];

    // dis for the 4 C-rows this lane maps to: node = tnode0 + lk*4 + r
    float dvv[4];
#pragma unroll
    for (int r = 0; r < 4; ++r) {
        int nd = tnode0 + lk * 4 + r;
        dvv[r] = dis[nd < n ? nd : (n - 1)];
    }

    // layer 1: 4 f-tiles of 16
#pragma unroll
    for (int T = 0; T < 4; ++T) {
        const float* bp = W1t + (size_t)(T * 16 + lm) * 32 + lk * 8;
        float4 bv0 = *(const float4*)bp;
        float4 bv1 = *(const float4*)(bp + 4);
        half8 bf;
        bf[0] = (_Float16)bv0.x; bf[1] = (_Float16)bv0.y;
        bf[2] = (_Float16)bv0.z; bf[3] = (_Float16)bv0.w;
        bf[4] = (_Float16)bv1.x; bf[5] = (_Float16)bv1.y;
        bf[6] = (_Float16)bv1.z; bf[7] = (_Float16)bv1.w;
        floatx4 c = {0.0f, 0.0f, 0.0f, 0.0f};
        c = __builtin_amdgcn_mfma_f32_16x16x32_f16(a1, bf, c, 0, 0, 0);
        float bias = b1[T * 16 + lm];
#pragma unroll
        for (int r = 0; r < 4; ++r) {
            float h = fmaxf(dvv[r] * c[r] + bias, 0.0f);
            shh[w][lk * 4 + r][T * 16 + lm] = (_Float16)h;
        }
    }

    // layer 2: A2 from per-wave LDS tile (node=lm), 2 K-steps x 2 f-tiles
    half8 a2k0 = *(const half8*)&shh[w][lm][lk * 8];
    half8 a2k1 = *(const half8*)&shh[w][lm][32 + lk * 8];
#pragma unroll
    for (int T = 0; T < 2; ++T) {
        const float* bp0 = W2t + (size_t)(T * 16 + lm) * 64 + lk * 8;
        const float* bp1 = bp0 + 32;
        float4 c0 = *(const float4*)bp0;
        float4 c1 = *(const float4*)(bp0 + 4);
        float4 c2 = *(const float4*)bp1;
        float4 c3 = *(const float4*)(bp1 + 4);
        half8 bf0, bf1;
        bf0[0] = (_Float16)c0.x; bf0[1] = (_Float16)c0.y;
        bf0[2] = (_Float16)c0.z; bf0[3] = (_Float16)c0.w;
        bf0[4] = (_Float16)c1.x; bf0[5] = (_Float16)c1.y;
        bf0[6] = (_Float16)c1.z; bf0[7] = (_Float16)c1.w;
        bf1[0] = (_Float16)c2.x; bf1[1] = (_Float16)c2.y;
        bf1[2] = (_Float16)c2.z; bf1[3] = (_Float16)c2.w;
        bf1[4] = (_Float16)c3.x; bf1[5] = (_Float16)c3.y;
        bf1[6] = (_Float16)c3.z; bf1[7] = (_Float16)c3.w;
        floatx4 acc = {0.0f, 0.0f, 0.0f, 0.0f};
        acc = __builtin_amdgcn_mfma_f32_16x16x32_f16(a2k0, bf0, acc, 0, 0, 0);
        acc = __builtin_amdgcn_mfma_f32_16x16x32_f16(a2k1, bf1, acc, 0, 0, 0);
#pragma unroll
        for (int r = 0; r < 4; ++r)
            sho[w][lk * 4 + r][T * 16 + lm] = (_Float16)(dvv[r] * acc[r]);
    }

    // coalesced store: lane -> node_local l>>2, f2-chunk (l&3)*8
    int nl = l >> 2, fc = (l & 3) * 8;
    int gnode = tnode0 + nl;
    if (gnode < n) {
        half8 v = *(const half8*)&sho[w][nl][fc];
        *(half8*)((_Float16*)xw2s + (size_t)gnode * 32 + fc) = v;
    }
}

// ---- layer 2 gather + bias + relu + head, fused ------------------------------

__global__ __launch_bounds__(TPB) void gather2_head_kernel(
        const __half* __restrict__ xw2s, const float* __restrict__ dis,
        const int2* __restrict__ oe, const int* __restrict__ slot,
        const float* __restrict__ b2, const float* __restrict__ Wl,
        const float* __restrict__ bl, float* __restrict__ out, int n) {
    int sub = threadIdx.x >> 5;
    int f = threadIdx.x & 31;
    int node = blockIdx.x * 8 + sub;
    if (node >= n) return;
    int2 se = oe[node];
    int j = se.x, end = se.y;
    float acc = __half2float(xw2s[(size_t)node * 32 + f]);
    for (; j + 7 < end; j += 8) {
        int s0 = slot[j], s1 = slot[j + 1], s2 = slot[j + 2], s3 = slot[j + 3];
        int s4 = slot[j + 4], s5 = slot[j + 5], s6 = slot[j + 6], s7 = slot[j + 7];
        float v0 = __half2float(xw2s[(size_t)s0 * 32 + f]);
        float v1 = __half2float(xw2s[(size_t)s1 * 32 + f]);
        float v2 = __half2float(xw2s[(size_t)s2 * 32 + f]);
        float v3 = __half2float(xw2s[(size_t)s3 * 32 + f]);
        float v4 = __half2float(xw2s[(size_t)s4 * 32 + f]);
        float v5 = __half2float(xw2s[(size_t)s5 * 32 + f]);
        float v6 = __half2float(xw2s[(size_t)s6 * 32 + f]);
        float v7 = __half2float(xw2s[(size_t)s7 * 32 + f]);
        acc += ((v0 + v1) + (v2 + v3)) + ((v4 + v5) + (v6 + v7));
    }
    for (; j + 3 < end; j += 4) {
        int s0 = slot[j], s1 = slot[j + 1], s2 = slot[j + 2], s3 = slot[j + 3];
        float v0 = __half2float(xw2s[(size_t)s0 * 32 + f]);
        float v1 = __half2float(xw2s[(size_t)s1 * 32 + f]);
        float v2 = __half2float(xw2s[(size_t)s2 * 32 + f]);
        float v3 = __half2float(xw2s[(size_t)s3 * 32 + f]);
        acc += (v0 + v1) + (v2 + v3);
    }
    for (; j < end; ++j) acc += __half2float(xw2s[(size_t)slot[j] * 32 + f]);
    float v = fmaxf(dis[node] * acc + b2[f], 0.0f);
    float c = v * Wl[f];
#pragma unroll
    for (int mm = 16; mm >= 1; mm >>= 1) c += __shfl_xor(c, mm, 32);
    if (f == 0) out[node] = c + bl[0];
}

// ---- host ------------------------------------------------------------------

extern "C" void kernel_launch(void* const* d_in, const int* in_sizes, int n_in,
                              void* d_out, int out_size, void* d_ws, size_t ws_size,
                              hipStream_t stream) {
    const float* x  = (const float*)d_in[0];
    const int*   ei = (const int*)d_in[1];
    const float* W1 = (const float*)d_in[2];
    const float* b1 = (const float*)d_in[3];
    const float* W2 = (const float*)d_in[4];
    const float* b2 = (const float*)d_in[5];
    const float* Wl = (const float*)d_in[6];
    const float* bl = (const float*)d_in[7];
    float* out = (float*)d_out;

    const int n = in_sizes[0] / 26;
    const int e = in_sizes[1] / 2;
    const int* src = ei;
    const int* dst = ei + e;

    const int nbuck = (n + NPB - 1) / NPB;   // 782 (<= NBUCK_MAX)
    const int eb    = (e + EPB - 1) / EPB;   // 293 scatter chunks

    auto align_up = [](size_t v) { return (v + 255) & ~(size_t)255; };
    char* p = (char*)d_ws;
    int*    bcnt    = (int*)p;     p += align_up((size_t)nbuck * 4);
    int*    sortedb = (int*)p;     p += align_up(((size_t)nbuck * CAP + 4096) * 4);
    int*    slot    = (int*)p;     p += align_up(((size_t)nbuck * CAP + 4096) * 4);
    float*  dis     = (float*)p;   p += align_up((size_t)n * 4);
    int2*   oe      = (int2*)p;    p += align_up((size_t)n * 8);
    float*  W1t     = (float*)p;   p += align_up(64 * 32 * 4);
    float*  W2t     = (float*)p;   p += align_up(32 * 64 * 4);
    __half* xs      = (__half*)p;  p += align_up((size_t)n * 32 * 2);
    __half* xw2s    = (__half*)p;  p += align_up((size_t)n * 32 * 2);

    // 1) build: zero bucket counters, scatter with bulk range claiming
    hipMemsetAsync(bcnt, 0, (size_t)nbuck * 4, stream);
    scatter_direct_kernel<<<eb, TPB, 0, stream>>>(src, dst, bcnt, sortedb,
                                                  W1, W2, W1t, W2t, e, nbuck);
    bucket_sort_fill_kernel<<<nbuck, TPB, 0, stream>>>(sortedb, bcnt, x, slot,
                                                       dis, oe, xs, n, nbuck);

    // 2) fused layer-1 gather + MFMA dense middle
    gather1_dense_kernel<<<(n + 63) / 64, TPB, 0, stream>>>(xs, oe, slot, dis,
                                                            W1t, b1, W2t, xw2s, n);

    // 3) layer 2 gather + bias + relu + head (fused)
    gather2_head_kernel<<<(n + 7) / 8, TPB, 0, stream>>>(xw2s, dis, oe, slot,
                                                         b2, Wl, bl, out, n);
}

// Round 14
// 97.299 us; speedup vs baseline: 1.7727x; 1.2857x over previous
//
#include <hip/hip_runtime.h>
#include <hip/hip_fp16.h>

// GCN 2-layer + linear head on MI355X.
// out = relu(agg(relu(agg(X)@W1 + b1)@W2) + b2) @ Wl + bl
// agg(Y) = D^-1/2 (A+I) D^-1/2 Y  (commutes with the dense transform; layer 1
// aggregates X at 26 feats, layer 2 transforms first at 32 feats).
//
// Build: fixed 2048-slot region per 128-node bucket; per-chunk LDS hist -> one
// global atomicAdd per (chunk,bucket) range claim -> LDS-atomic scatter. Then
// per-bucket degree/extents/node-sort/prescale (xs fp16, padded 64B rows).
// Gathers (R14): 4-lane groups, one node/group, half8 (16B) per lane -> 8x fewer
// VMEM instructions per edge, 16 edge streams per wave, unroll-4 MLP.
// Dense middle: MFMA (16x16x32 f16), fused behind gather1 (LDS handoff).
// Fragment maps (gfx950, HW-verified): A/B non-K index = lane&15, K-slice =
// (lane>>4)*8; C/D col=lane&15, row=(lane>>4)*4+reg.

#define TPB 256
#define NPB 128              // nodes per bucket (dstlow = 7 bits)
#define CAP 2048             // slots per bucket region (avg fill 1534, 13 sigma safe)
#define EPB 4096             // edges per scatter chunk
#define NBUCK_MAX 1024

typedef _Float16 half8 __attribute__((ext_vector_type(8)));
typedef float floatx4 __attribute__((ext_vector_type(4)));

// ---- scatter: LDS hist -> bulk range claim -> scatter; + W transpose (blk 0) --

__global__ __launch_bounds__(TPB) void scatter_direct_kernel(
        const int* __restrict__ src, const int* __restrict__ dst,
        int* __restrict__ bcnt, int* __restrict__ sortedb,
        const float* __restrict__ W1, const float* __restrict__ W2,
        float* __restrict__ W1t, float* __restrict__ W2t,
        int e, int nbuck) {
    __shared__ int lh[NBUCK_MAX];
    int t = threadIdx.x;
    for (int b = t; b < nbuck; b += TPB) lh[b] = 0;
    __syncthreads();
    int j0 = blockIdx.x * EPB;
    int j1 = min(e, j0 + EPB);
    for (int j = j0 + t; j < j1; j += TPB)
        atomicAdd(&lh[dst[j] >> 7], 1);              // LDS hist
    __syncthreads();
    for (int b = t; b < nbuck; b += TPB) {
        int c = lh[b];
        int base = c ? atomicAdd(&bcnt[b], c) : 0;   // bulk global claim
        lh[b] = b * CAP + base;                      // running write ptr
    }
    __syncthreads();
    for (int j = j0 + t; j < j1; j += TPB) {
        int d = dst[j];
        int s = src[j];
        int pos = atomicAdd(&lh[d >> 7], 1);         // LDS atomic only
        sortedb[pos] = (s << 7) | (d & 127);
    }
    if (blockIdx.x == 0) {
        // W1t[64][32]: W1t[f*32+k] = W1[k*64+f] (k<26; pad 0). W2t[32][64].
        for (int q = t; q < 64 * 32; q += TPB) {
            int f = q >> 5, k = q & 31;
            W1t[q] = (k < 26) ? W1[k * 64 + f] : 0.0f;
        }
        for (int q = t; q < 32 * 64; q += TPB) {
            int f = q >> 6, k = q & 63;
            W2t[q] = W2[k * 32 + f];
        }
    }
}

// ---- per bucket: degree count -> dis/extents, node-sorted slots, prescale ----

__global__ __launch_bounds__(TPB) void bucket_sort_fill_kernel(
        const int* __restrict__ sortedb, const int* __restrict__ bcnt,
        const float* __restrict__ x,
        int* __restrict__ slot, float* __restrict__ dis, int2* __restrict__ oe,
        __half* __restrict__ xs, int n, int nbuck) {
    __shared__ int c[NPB];
    __shared__ int ptr[NPB];
    __shared__ float sdis[NPB];
    int b = blockIdx.x, t = threadIdx.x;
    if (t < NPB) c[t] = 0;
    __syncthreads();
    int start = b * CAP;
    int end = start + bcnt[b];
    for (int j = start + t; j < end; j += TPB)
        atomicAdd(&c[sortedb[j] & 127], 1);
    __syncthreads();
    int mycnt = (t < NPB) ? c[t] : 0;
    // inclusive Hillis-Steele scan over 128 entries
    for (int d = 1; d < NPB; d <<= 1) {
        int v = 0;
        if (t < NPB && t >= d) v = c[t - d];
        __syncthreads();
        if (t < NPB) c[t] += v;
        __syncthreads();
    }
    if (t < NPB) {
        int excl = c[t] - mycnt;
        ptr[t] = excl;
        float dv = rsqrtf((float)mycnt + 1.0f);
        sdis[t] = dv;
        int g = b * NPB + t;
        if (g < n) {
            dis[g] = dv;
            oe[g] = make_int2(start + excl, start + excl + mycnt);
        }
    }
    __syncthreads();
    for (int j = start + t; j < end; j += TPB) {
        int w = sortedb[j];
        int pos = atomicAdd(&ptr[w & 127], 1);  // LDS atomic only
        slot[start + pos] = w >> 7;
    }
    // fused prescale (fp16 padded 64B rows)
    int base = b * NPB;
    for (int i = t; i < NPB * 32; i += TPB) {
        int r = i >> 5, lane = i & 31;
        int g = base + r;
        if (g < n)
            xs[(size_t)g * 32 + lane] = __float2half(
                (lane < 26) ? sdis[r] * x[(size_t)g * 26 + lane] : 0.0f);
    }
}

// ---- fused gather1 + MFMA dense middle --------------------------------------
// Phase A: 64x 4-lane groups, one node each; half8/lane, unroll-4 edge streams.
// Phase B: per-wave 16-node tile MFMA; h1 -> per-wave LDS; fp16 store.

__global__ __launch_bounds__(TPB) void gather1_dense_kernel(
        const __half* __restrict__ xs, const int2* __restrict__ oe,
        const int* __restrict__ slot, const float* __restrict__ dis,
        const float* __restrict__ W1t, const float* __restrict__ b1,
        const float* __restrict__ W2t, __half* __restrict__ xw2s, int n) {
    __shared__ _Float16 ssum[64][40];     // agg(X) tile: 64 nodes x 32 f (+8 pad)
    __shared__ _Float16 shh[4][16][72];   // h1: per-wave 16x64 (+8 pad)
    __shared__ _Float16 sho[4][16][40];   // out: per-wave 16x32 (+8 pad)
    int t = threadIdx.x;
    int node0 = blockIdx.x * 64;
    const _Float16* xsp = (const _Float16*)xs;

    // ---- phase A: gather (4 lanes per node, 8 feats per lane)
    {
        int g = t >> 2;              // 0..63 : node group
        int fl = (t & 3) * 8;        // feature chunk base
        int node = node0 + g;
        float accf[8];
#pragma unroll
        for (int k = 0; k < 8; ++k) accf[k] = 0.0f;
        if (node < n) {
            half8 ownv = *(const half8*)(xsp + (size_t)node * 32 + fl);
#pragma unroll
            for (int k = 0; k < 8; ++k) accf[k] = (float)ownv[k];
            int2 se = oe[node];
            int j = se.x, end = se.y;
            for (; j + 3 < end; j += 4) {
                int s0 = slot[j], s1 = slot[j + 1], s2 = slot[j + 2], s3 = slot[j + 3];
                half8 v0 = *(const half8*)(xsp + (size_t)s0 * 32 + fl);
                half8 v1 = *(const half8*)(xsp + (size_t)s1 * 32 + fl);
                half8 v2 = *(const half8*)(xsp + (size_t)s2 * 32 + fl);
                half8 v3 = *(const half8*)(xsp + (size_t)s3 * 32 + fl);
#pragma unroll
                for (int k = 0; k < 8; ++k)
                    accf[k] += ((float)v0[k] + (float)v1[k]) + ((float)v2[k] + (float)v3[k]);
            }
            for (; j < end; ++j) {
                int s = slot[j];
                half8 v = *(const half8*)(xsp + (size_t)s * 32 + fl);
#pragma unroll
                for (int k = 0; k < 8; ++k) accf[k] += (float)v[k];
            }
        }
        half8 o;
#pragma unroll
        for (int k = 0; k < 8; ++k) o[k] = (_Float16)accf[k];
        *(half8*)&ssum[g][fl] = o;
    }
    __syncthreads();

    // ---- phase B: MFMA dense middle
    int w = t >> 6, l = t & 63;
    int tnode0 = node0 + w * 16;
    int lm = l & 15;           // A/B non-K index
    int lk = l >> 4;           // K-slice id 0..3

    half8 a1 = *(const half8*)&ssum[w * 16 + lm][lk * 8];

    float dvv[4];
#pragma unroll
    for (int r = 0; r < 4; ++r) {
        int nd = tnode0 + lk * 4 + r;
        dvv[r] = dis[nd < n ? nd : (n - 1)];
    }

    // layer 1: 4 f-tiles of 16
#pragma unroll
    for (int T = 0; T < 4; ++T) {
        const float* bp = W1t + (size_t)(T * 16 + lm) * 32 + lk * 8;
        float4 bv0 = *(const float4*)bp;
        float4 bv1 = *(const float4*)(bp + 4);
        half8 bf;
        bf[0] = (_Float16)bv0.x; bf[1] = (_Float16)bv0.y;
        bf[2] = (_Float16)bv0.z; bf[3] = (_Float16)bv0.w;
        bf[4] = (_Float16)bv1.x; bf[5] = (_Float16)bv1.y;
        bf[6] = (_Float16)bv1.z; bf[7] = (_Float16)bv1.w;
        floatx4 c = {0.0f, 0.0f, 0.0f, 0.0f};
        c = __builtin_amdgcn_mfma_f32_16x16x32_f16(a1, bf, c, 0, 0, 0);
        float bias = b1[T * 16 + lm];
#pragma unroll
        for (int r = 0; r < 4; ++r) {
            float h = fmaxf(dvv[r] * c[r] + bias, 0.0f);
            shh[w][lk * 4 + r][T * 16 + lm] = (_Float16)h;
        }
    }

    // layer 2: A2 from per-wave LDS tile (node=lm), 2 K-steps x 2 f-tiles
    half8 a2k0 = *(const half8*)&shh[w][lm][lk * 8];
    half8 a2k1 = *(const half8*)&shh[w][lm][32 + lk * 8];
#pragma unroll
    for (int T = 0; T < 2; ++T) {
        const float* bp0 = W2t + (size_t)(T * 16 + lm) * 64 + lk * 8;
        const float* bp1 = bp0 + 32;
        float4 c0 = *(const float4*)bp0;
        float4 c1 = *(const float4*)(bp0 + 4);
        float4 c2 = *(const float4*)bp1;
        float4 c3 = *(const float4*)(bp1 + 4);
        half8 bf0, bf1;
        bf0[0] = (_Float16)c0.x; bf0[1] = (_Float16)c0.y;
        bf0[2] = (_Float16)c0.z; bf0[3] = (_Float16)c0.w;
        bf0[4] = (_Float16)c1.x; bf0[5] = (_Float16)c1.y;
        bf0[6] = (_Float16)c1.z; bf0[7] = (_Float16)c1.w;
        bf1[0] = (_Float16)c2.x; bf1[1] = (_Float16)c2.y;
        bf1[2] = (_Float16)c2.z; bf1[3] = (_Float16)c2.w;
        bf1[4] = (_Float16)c3.x; bf1[5] = (_Float16)c3.y;
        bf1[6] = (_Float16)c3.z; bf1[7] = (_Float16)c3.w;
        floatx4 acc = {0.0f, 0.0f, 0.0f, 0.0f};
        acc = __builtin_amdgcn_mfma_f32_16x16x32_f16(a2k0, bf0, acc, 0, 0, 0);
        acc = __builtin_amdgcn_mfma_f32_16x16x32_f16(a2k1, bf1, acc, 0, 0, 0);
#pragma unroll
        for (int r = 0; r < 4; ++r)
            sho[w][lk * 4 + r][T * 16 + lm] = (_Float16)(dvv[r] * acc[r]);
    }

    // coalesced store: lane -> node_local l>>2, f2-chunk (l&3)*8
    int nl = l >> 2, fc = (l & 3) * 8;
    int gnode = tnode0 + nl;
    if (gnode < n) {
        half8 v = *(const half8*)&sho[w][nl][fc];
        *(half8*)((_Float16*)xw2s + (size_t)gnode * 32 + fc) = v;
    }
}

// ---- layer 2 gather + bias + relu + head (4-lane groups, half8/lane) ---------

__global__ __launch_bounds__(TPB) void gather2_head_kernel(
        const __half* __restrict__ xw2s, const float* __restrict__ dis,
        const int2* __restrict__ oe, const int* __restrict__ slot,
        const float* __restrict__ b2, const float* __restrict__ Wl,
        const float* __restrict__ bl, float* __restrict__ out, int n) {
    int t = threadIdx.x;
    int g = t >> 2;              // 0..63 : node group
    int fl = (t & 3) * 8;        // feature chunk base
    int node = blockIdx.x * 64 + g;
    if (node >= n) return;
    const _Float16* xp = (const _Float16*)xw2s;

    float accf[8];
    half8 ownv = *(const half8*)(xp + (size_t)node * 32 + fl);
#pragma unroll
    for (int k = 0; k < 8; ++k) accf[k] = (float)ownv[k];
    int2 se = oe[node];
    int j = se.x, end = se.y;
    for (; j + 3 < end; j += 4) {
        int s0 = slot[j], s1 = slot[j + 1], s2 = slot[j + 2], s3 = slot[j + 3];
        half8 v0 = *(const half8*)(xp + (size_t)s0 * 32 + fl);
        half8 v1 = *(const half8*)(xp + (size_t)s1 * 32 + fl);
        half8 v2 = *(const half8*)(xp + (size_t)s2 * 32 + fl);
        half8 v3 = *(const half8*)(xp + (size_t)s3 * 32 + fl);
#pragma unroll
        for (int k = 0; k < 8; ++k)
            accf[k] += ((float)v0[k] + (float)v1[k]) + ((float)v2[k] + (float)v3[k]);
    }
    for (; j < end; ++j) {
        int s = slot[j];
        half8 v = *(const half8*)(xp + (size_t)s * 32 + fl);
#pragma unroll
        for (int k = 0; k < 8; ++k) accf[k] += (float)v[k];
    }

    float dv = dis[node];
    float4 bq0 = *(const float4*)(b2 + fl);
    float4 bq1 = *(const float4*)(b2 + fl + 4);
    float4 wq0 = *(const float4*)(Wl + fl);
    float4 wq1 = *(const float4*)(Wl + fl + 4);
    float bb[8] = {bq0.x, bq0.y, bq0.z, bq0.w, bq1.x, bq1.y, bq1.z, bq1.w};
    float wl[8] = {wq0.x, wq0.y, wq0.z, wq0.w, wq1.x, wq1.y, wq1.z, wq1.w};
    float c = 0.0f;
#pragma unroll
    for (int k = 0; k < 8; ++k) {
        float v = fmaxf(dv * accf[k] + bb[k], 0.0f);
        c += v * wl[k];
    }
    c += __shfl_xor(c, 1);
    c += __shfl_xor(c, 2);
    if ((t & 3) == 0) out[node] = c + bl[0];
}

// ---- host ------------------------------------------------------------------

extern "C" void kernel_launch(void* const* d_in, const int* in_sizes, int n_in,
                              void* d_out, int out_size, void* d_ws, size_t ws_size,
                              hipStream_t stream) {
    const float* x  = (const float*)d_in[0];
    const int*   ei = (const int*)d_in[1];
    const float* W1 = (const float*)d_in[2];
    const float* b1 = (const float*)d_in[3];
    const float* W2 = (const float*)d_in[4];
    const float* b2 = (const float*)d_in[5];
    const float* Wl = (const float*)d_in[6];
    const float* bl = (const float*)d_in[7];
    float* out = (float*)d_out;

    const int n = in_sizes[0] / 26;
    const int e = in_sizes[1] / 2;
    const int* src = ei;
    const int* dst = ei + e;

    const int nbuck = (n + NPB - 1) / NPB;   // 782 (<= NBUCK_MAX)
    const int eb    = (e + EPB - 1) / EPB;   // 293 scatter chunks

    auto align_up = [](size_t v) { return (v + 255) & ~(size_t)255; };
    char* p = (char*)d_ws;
    int*    bcnt    = (int*)p;     p += align_up((size_t)nbuck * 4);
    int*    sortedb = (int*)p;     p += align_up(((size_t)nbuck * CAP + 4096) * 4);
    int*    slot    = (int*)p;     p += align_up(((size_t)nbuck * CAP + 4096) * 4);
    float*  dis     = (float*)p;   p += align_up((size_t)n * 4);
    int2*   oe      = (int2*)p;    p += align_up((size_t)n * 8);
    float*  W1t     = (float*)p;   p += align_up(64 * 32 * 4);
    float*  W2t     = (float*)p;   p += align_up(32 * 64 * 4);
    __half* xs      = (__half*)p;  p += align_up((size_t)n * 32 * 2);
    __half* xw2s    = (__half*)p;  p += align_up((size_t)n * 32 * 2);

    // 1) build: zero bucket counters, scatter with bulk range claiming
    hipMemsetAsync(bcnt, 0, (size_t)nbuck * 4, stream);
    scatter_direct_kernel<<<eb, TPB, 0, stream>>>(src, dst, bcnt, sortedb,
                                                  W1, W2, W1t, W2t, e, nbuck);
    bucket_sort_fill_kernel<<<nbuck, TPB, 0, stream>>>(sortedb, bcnt, x, slot,
                                                       dis, oe, xs, n, nbuck);

    // 2) fused layer-1 gather + MFMA dense middle
    gather1_dense_kernel<<<(n + 63) / 64, TPB, 0, stream>>>(xs, oe, slot, dis,
                                                            W1t, b1, W2t, xw2s, n);

    // 3) layer 2 gather + bias + relu + head (fused)
    gather2_head_kernel<<<(n + 63) / 64, TPB, 0, stream>>>(xw2s, dis, oe, slot,
                                                           b2, Wl, bl, out, n);
}